// Round 13
// baseline (345.981 us; speedup 1.0000x reference)
//
#include <hip/hip_runtime.h>

#define NF 128      // feature width for x / hidden layers
#define CHUNK 8192  // edges per block in CSR-build phase 1

typedef __attribute__((ext_vector_type(8))) short bf16x8;
typedef __attribute__((ext_vector_type(4))) float f32x4;
typedef __attribute__((ext_vector_type(2))) float f32x2;

__device__ __forceinline__ unsigned short f2b(float f) {
    unsigned int u = __float_as_uint(f);
    unsigned int r = (u + 0x7fffu + ((u >> 16) & 1u)) >> 16;  // round-nearest-even
    return (unsigned short)r;
}

// async global->LDS, 16B per lane. LDS dest = wave-uniform base (+lane*16 by HW);
// global src is per-lane.
__device__ __forceinline__ void gld_lds16(const void* g, const void* l) {
    __builtin_amdgcn_global_load_lds(
        (const __attribute__((address_space(1))) unsigned int*)(unsigned long long)g,
        (__attribute__((address_space(3))) unsigned int*)(unsigned int)(unsigned long long)l,
        16, 0, 0);
}

// ========== fused prep: cvt(+fp8) | wcat0 | wcat1 | wstack | hist ============

__global__ __launch_bounds__(256) void prep_kernel(
        const float* __restrict__ x, unsigned short* __restrict__ xb,
        unsigned char* __restrict__ x8, int n4,
        const float* __restrict__ Wl0, const float* __restrict__ Wr0, unsigned short* __restrict__ Wc0,
        const float* __restrict__ Wl1, const float* __restrict__ Wr1, unsigned short* __restrict__ Wc1,
        const float* __restrict__ Wl2, const float* __restrict__ Wr2, const float* __restrict__ b2,
        unsigned short* __restrict__ Wst, float* __restrict__ bst,
        const int* __restrict__ dst, int* __restrict__ hist, int E, int NB,
        int bCvt, int bW0, int bW1, int bWs) {
    __shared__ int hsh[512];
    const int blk = blockIdx.x;
    const int tid = threadIdx.x;
    if (blk < bCvt) {
        int i = blk * 256 + tid;
        if (i < n4) {
            float4 v = *(const float4*)&x[(size_t)i * 4];
            uint2 o;
            o.x = (unsigned int)f2b(v.x) | ((unsigned int)f2b(v.y) << 16);
            o.y = (unsigned int)f2b(v.z) | ((unsigned int)f2b(v.w) << 16);
            *(uint2*)&xb[(size_t)i * 4] = o;
            unsigned p = __builtin_amdgcn_cvt_pk_fp8_f32(v.x, v.y, 0, false);
            p = __builtin_amdgcn_cvt_pk_fp8_f32(v.z, v.w, p, true);
            *(unsigned int*)&x8[(size_t)i * 4] = p;
        }
    } else if (blk < bW1) {
        const bool first = blk < bW0;
        int i = (blk - (first ? bCvt : bW0)) * 256 + tid;  // < 16384
        const float* Wl = first ? Wl0 : Wl1;
        const float* Wr = first ? Wr0 : Wr1;
        unsigned short* Wc = first ? Wc0 : Wc1;
        int f = i >> 7, k = i & 127;
        Wc[f * 256 + k] = f2b(Wl[i]);
        Wc[f * 256 + 128 + k] = f2b(Wr[i]);
    } else if (blk < bWs) {
        int i = (blk - bW1) * 256 + tid;  // < 8192
        int f = i >> 7, k = i & 127;
        Wst[f * 128 + k] = f2b(Wl2[i]);
        Wst[(f + 64) * 128 + k] = f2b(Wr2[i]);
        if (k == 0) {
            bst[f] = 0.f;
            bst[f + 64] = b2[f];
        }
    } else {
        const int hb = blk - bWs;  // hist block
        for (int i = tid; i < NB; i += 256) hsh[i] = 0;
        __syncthreads();
        const int e0 = hb * CHUNK;
        for (int i = tid; i < CHUNK; i += 256) {
            int e = e0 + i;
            if (e < E) atomicAdd(&hsh[dst[e] >> 8], 1);
        }
        __syncthreads();
        for (int i = tid; i < NB; i += 256) hist[hb * NB + i] = hsh[i];
    }
}

// ================= CSR build scan chain =================

__global__ __launch_bounds__(256) void sb_sum(const int* __restrict__ hist,
                                              int* __restrict__ bsum,
                                              int T, int NB, int NBLK) {
    int i = blockIdx.x * 256 + threadIdx.x;
    int v = 0;
    if (i < T) {
        int b = i / NBLK, blk = i - b * NBLK;
        v = hist[blk * NB + b];
    }
#pragma unroll
    for (int d = 32; d; d >>= 1) v += __shfl_down(v, d, 64);
    __shared__ int wsum[4];
    if ((threadIdx.x & 63) == 0) wsum[threadIdx.x >> 6] = v;
    __syncthreads();
    if (threadIdx.x == 0) bsum[blockIdx.x] = wsum[0] + wsum[1] + wsum[2] + wsum[3];
}

__global__ __launch_bounds__(1024) void sb_scan(const int* __restrict__ bsum,
                                                int* __restrict__ bpre, int NS) {
    __shared__ int s[1024];
    int t = threadIdx.x;
    int v = (t < NS) ? bsum[t] : 0;
    s[t] = v;
    __syncthreads();
    for (int d = 1; d < 1024; d <<= 1) {
        int u = (t >= d) ? s[t - d] : 0;
        __syncthreads();
        s[t] += u;
        __syncthreads();
    }
    if (t < NS) bpre[t] = s[t] - v;
}

__global__ __launch_bounds__(256) void sb_apply(const int* __restrict__ hist,
                                                const int* __restrict__ bpre,
                                                int* __restrict__ base,
                                                int* __restrict__ bstart,
                                                int T, int NB, int NBLK, int E) {
    __shared__ int s[256];
    int i = blockIdx.x * 256 + threadIdx.x;
    int t = threadIdx.x;
    int v = 0;
    int b = 0, blk = 0;
    if (i < T) {
        b = i / NBLK;
        blk = i - b * NBLK;
        v = hist[blk * NB + b];
    }
    s[t] = v;
    __syncthreads();
    for (int d = 1; d < 256; d <<= 1) {
        int u = (t >= d) ? s[t - d] : 0;
        __syncthreads();
        s[t] += u;
        __syncthreads();
    }
    if (i < T) {
        int val = bpre[blockIdx.x] + s[t] - v;
        base[i] = val;
        if (blk == 0) bstart[b] = val;
        if (i == 0) bstart[NB] = E;
    }
}

__global__ __launch_bounds__(256) void scat_kernel(const int* __restrict__ src,
                                                   const int* __restrict__ dst,
                                                   const int* __restrict__ base,
                                                   unsigned int* __restrict__ recs,
                                                   int E, int NB, int NBLK) {
    __shared__ int cur[512];
    const int blk = blockIdx.x;
    for (int b = threadIdx.x; b < NB; b += 256) cur[b] = base[b * NBLK + blk];
    __syncthreads();
    const int e0 = blk * CHUNK;
    for (int i = threadIdx.x; i < CHUNK; i += 256) {
        int e = e0 + i;
        if (e >= E) continue;
        int d = dst[e];
        int b = d >> 8;
        int pos = atomicAdd(&cur[b], 1);
        recs[pos] = (unsigned int)src[e] | ((unsigned int)(d & 255) << 24);
    }
}

__global__ __launch_bounds__(256) void csr_kernel(const unsigned int* __restrict__ recs,
                                                  const int* __restrict__ bstart,
                                                  int* __restrict__ offs,
                                                  float* __restrict__ rdeg,
                                                  int* __restrict__ csr,
                                                  int N, int E) {
    __shared__ int cnt[256];
    __shared__ int sc[256];
    __shared__ int cur[256];
    const int b = blockIdx.x;
    const int t = threadIdx.x;
    const int s0 = bstart[b], s1 = bstart[b + 1];
    cnt[t] = 0;
    __syncthreads();
    for (int i = s0 + t; i < s1; i += 256) atomicAdd(&cnt[recs[i] >> 24], 1);
    __syncthreads();
    int v = cnt[t];
    sc[t] = v;
    __syncthreads();
    for (int d = 1; d < 256; d <<= 1) {
        int u = (t >= d) ? sc[t - d] : 0;
        __syncthreads();
        sc[t] += u;
        __syncthreads();
    }
    int excl = sc[t] - v;
    int node = b * 256 + t;
    if (node < N) {
        offs[node] = s0 + excl;
        rdeg[node] = 1.0f / (float)(v > 1 ? v : 1);
        if (node == N - 1) offs[N] = E;
    }
    cur[t] = s0 + excl;
    __syncthreads();
    for (int i = s0 + t; i < s1; i += 256) {
        unsigned int r = recs[i];
        int pos = atomicAdd(&cur[r >> 24], 1);
        csr[pos] = (int)(r & 0xFFFFFFu);
    }
}

// ========== FUSED LAYER (0/1): gather-mean(fp8) + dual-linear GEMM ===========
// Block = 64 nodes, 4 waves. Phase A: stage root rows into Ar (async, issued
// first so latency hides under gather); each wave gathers means for 16 nodes
// (identical fp8 math as before) -> bf16 pairs ds_written into Am.
// Phase B: MFMA k-loop; A = [Am | Ar], W direct-global (L2-hot).
// Gather waves of co-resident blocks hide the W-load/MFMA stalls of others.

template <bool OUT8>
__global__ __launch_bounds__(256) void fused_layer(
        const unsigned char* __restrict__ g8,     // gather src [N][128] fp8
        const unsigned short* __restrict__ root,  // root rows [N][128] bf16
        const int* __restrict__ offs, const int* __restrict__ csr,
        const float* __restrict__ rdeg,
        const unsigned short* __restrict__ Wcat,  // [128][256] bf16
        const float* __restrict__ bias,           // [128] fp32
        unsigned short* __restrict__ outb,
        unsigned char* __restrict__ out8,
        int N) {
    __shared__ unsigned short Am[64 * 128];   // mean half, 16KB, 256B rows
    __shared__ unsigned short Ar[64 * 128];   // root half, 16KB

    const int tid = threadIdx.x, wid = tid >> 6, lane = tid & 63;
    const int m0 = blockIdx.x * 64;
    char* Amc = (char*)Am;
    char* Arc = (char*)Ar;
    const char* Rb = (const char*)root;
    const char* Wb = (const char*)Wcat;

    // ---- stage root rows (issued first; drains during gather) ----
#pragma unroll
    for (int i = 0; i < 4; ++i) {
        int off = wid * 4096 + i * 1024 + lane * 16;
        int row = off >> 8, c = off & 255;
        int c2 = c ^ ((row & 7) << 4);
        gld_lds16(Rb + (size_t)(m0 + row) * 256 + c2, Arc + wid * 4096 + i * 1024);
    }

    // ---- gather phase: wave wid handles local nodes wid*16 .. wid*16+15 ----
    const char* __restrict__ hb = (const char*)g8;
    const unsigned lane2 = (unsigned)lane * 2u;
    for (int t = 0; t < 16; ++t) {
        const int node = m0 + wid * 16 + t;
        if (node >= N) break;
        const int s0 = offs[node], s1 = offs[node + 1];
        f32x2 acc = {0.f, 0.f};
        for (int base = s0; base < s1; base += 64) {
            const int cnt = min(64, s1 - base);
            const int boff = csr[base + min(lane, cnt - 1)] << 7;
            int j = 0;
#define AGG8_GROUP(NG)                                                         \
            {                                                                  \
                unsigned o[NG];                                                \
                _Pragma("unroll")                                              \
                for (int k = 0; k < NG; ++k)                                   \
                    o[k] = (unsigned)__shfl(boff, j + k, 64) + lane2;          \
                unsigned int v[NG];                                            \
                _Pragma("unroll")                                              \
                for (int k = 0; k < NG; ++k)                                   \
                    v[k] = *(const unsigned short*)(hb + o[k]);                \
                _Pragma("unroll")                                              \
                for (int k = 0; k < NG; ++k)                                   \
                    acc += __builtin_amdgcn_cvt_pk_f32_fp8(v[k], false);       \
                j += NG;                                                       \
            }
            while (j + 16 <= cnt) AGG8_GROUP(16)
            if (cnt & 8) AGG8_GROUP(8)
            if (cnt & 4) AGG8_GROUP(4)
            if (cnt & 2) AGG8_GROUP(2)
            if (cnt & 1) AGG8_GROUP(1)
#undef AGG8_GROUP
        }
        const float r = rdeg[node];
        const unsigned int mo = (unsigned int)f2b(acc.x * r) |
                                ((unsigned int)f2b(acc.y * r) << 16);
        const int lrow = wid * 16 + t;
        const unsigned doff = (unsigned)lrow * 256 +
                              (((unsigned)lane * 4u) ^ (((unsigned)(lrow & 7)) << 4));
        *(unsigned int*)(Amc + doff) = mo;   // conflict-free: consecutive words
    }
    asm volatile("s_waitcnt vmcnt(0)" ::: "memory");
    __syncthreads();

    // ---- GEMM phase: 4 waves = 2M x 2N; MI=2, NI=4 ----
    constexpr int MI = 2;
    constexpr int NI = 4;
    const int lm = lane & 15, ko = lane >> 4;
    const int wmBase = (wid >> 1) * 32;
    const int wnBase = (wid & 1) * 64;

    f32x4 acc[MI][NI];
#pragma unroll
    for (int i = 0; i < MI; ++i)
#pragma unroll
        for (int j = 0; j < NI; ++j)
            acc[i][j] = (f32x4){0.f, 0.f, 0.f, 0.f};

#pragma unroll
    for (int ks = 0; ks < 8; ++ks) {
        const int kb = ks * 64 + ko * 16;      // 0..511 over [mean|root]
        const int kbl = kb & 255;              // offset within 256B half-row
        const char* Abase = (ks < 4) ? Amc : Arc;
        bf16x8 a[MI], b[NI];
#pragma unroll
        for (int j = 0; j < NI; ++j) {
            int row = wnBase + j * 16 + lm;
            b[j] = *(const bf16x8*)(Wb + row * 512 + kb);   // direct global (L2-hot)
        }
#pragma unroll
        for (int i = 0; i < MI; ++i) {
            int row = wmBase + i * 16 + lm;
            a[i] = *(const bf16x8*)(Abase + row * 256 + (kbl ^ ((row & 7) << 4)));
        }
#pragma unroll
        for (int i = 0; i < MI; ++i)
#pragma unroll
            for (int j = 0; j < NI; ++j)
                acc[i][j] = __builtin_amdgcn_mfma_f32_16x16x32_bf16(b[j], a[i], acc[i][j], 0, 0, 0);
    }

#pragma unroll
    for (int i = 0; i < MI; ++i) {
        const int node = m0 + wmBase + i * 16 + lm;
        if (node < N) {
#pragma unroll
            for (int j = 0; j < NI; ++j) {
                const int col0 = wnBase + j * 16 + ko * 4;
                const float4 bv = *(const float4*)&bias[col0];
                float v0 = fmaxf(acc[i][j][0] + bv.x, 0.f);
                float v1 = fmaxf(acc[i][j][1] + bv.y, 0.f);
                float v2 = fmaxf(acc[i][j][2] + bv.z, 0.f);
                float v3 = fmaxf(acc[i][j][3] + bv.w, 0.f);
                uint2 o;
                o.x = (unsigned int)f2b(v0) | ((unsigned int)f2b(v1) << 16);
                o.y = (unsigned int)f2b(v2) | ((unsigned int)f2b(v3) << 16);
                *(uint2*)&outb[(size_t)node * 128 + col0] = o;
                if (OUT8) {
                    unsigned p = __builtin_amdgcn_cvt_pk_fp8_f32(v0, v1, 0, false);
                    p = __builtin_amdgcn_cvt_pk_fp8_f32(v2, v3, p, true);
                    *(unsigned int*)&out8[(size_t)node * 128 + col0] = p;
                }
            }
        }
    }
}

// ---- layer-2 final agg: out[i] = mean_j zl[j] + zr[i]  (fp32 out) -----------
// One node/wave; feature == lane (64 features); single-segment 128B row loads.

__global__ __launch_bounds__(256) void agg2_kernel(
        const unsigned short* __restrict__ z, const int* __restrict__ offs,
        const int* __restrict__ csr, const float* __restrict__ rdeg,
        float* __restrict__ out, int N) {
    const int node = blockIdx.x * 4 + (threadIdx.x >> 6);
    const int lane = threadIdx.x & 63;
    if (node >= N) return;
    const int s0 = offs[node], s1 = offs[node + 1];
    const char* __restrict__ zb = (const char*)z;
    const unsigned lane2 = (unsigned)lane * 2u;
    float acc = 0.f;
    for (int base = s0; base < s1; base += 64) {
        const int cnt = min(64, s1 - base);
        const int boff = csr[base + min(lane, cnt - 1)] << 8;  // zl = first 128B of 256B row
        int j = 0;
#define AGG2_GROUP(NG)                                                         \
        {                                                                      \
            unsigned o[NG];                                                    \
            _Pragma("unroll")                                                  \
            for (int k = 0; k < NG; ++k)                                       \
                o[k] = (unsigned)__shfl(boff, j + k, 64) + lane2;              \
            unsigned int v[NG];                                                \
            _Pragma("unroll")                                                  \
            for (int k = 0; k < NG; ++k)                                       \
                v[k] = *(const unsigned short*)(zb + o[k]);                    \
            _Pragma("unroll")                                                  \
            for (int k = 0; k < NG; ++k)                                       \
                acc += __uint_as_float(v[k] << 16);                            \
            j += NG;                                                           \
        }
        while (j + 16 <= cnt) AGG2_GROUP(16)
        if (cnt & 8) AGG2_GROUP(8)
        if (cnt & 4) AGG2_GROUP(4)
        if (cnt & 2) AGG2_GROUP(2)
        if (cnt & 1) AGG2_GROUP(1)
#undef AGG2_GROUP
    }
    float r = rdeg[node];
    unsigned int vr = *(const unsigned short*)(zb + (size_t)node * 256 + 128 + lane2);
    out[(size_t)node * 64 + lane] = acc * r + __uint_as_float(vr << 16);
}

// ---------- MFMA GEMM (layer 2): z = h @ Wst^T + bst  (K=128, bf16 out) -------
// BM=64 tile (16KB LDS).

__global__ __launch_bounds__(256) void gemmz_kernel(
        const unsigned short* __restrict__ A,    // [N][128] bf16
        const unsigned short* __restrict__ W,    // [128][128] bf16
        const float* __restrict__ bias,          // [128] fp32
        unsigned short* __restrict__ outb,       // [N][128] bf16
        int N) {
    __shared__ unsigned short As[64 * 128];   // 16KB

    const int tid = threadIdx.x, wid = tid >> 6, lane = tid & 63;
    const int m0 = blockIdx.x * 64;
    char* Ac = (char*)As;
    const char* Ab = (const char*)A;
    const char* Wb = (const char*)W;

#pragma unroll
    for (int i = 0; i < 4; ++i) {
        int off = wid * 4096 + i * 1024 + lane * 16;
        int row = off >> 8, c = off & 255;
        int c2 = c ^ ((row & 7) << 4);
        gld_lds16(Ab + (size_t)(m0 + row) * 256 + c2, Ac + wid * 4096 + i * 1024);
    }
    asm volatile("s_waitcnt vmcnt(0)" ::: "memory");
    __syncthreads();

    constexpr int MI = 2;
    constexpr int NI = 4;
    const int lm = lane & 15, ko = lane >> 4;
    const int wmBase = (wid >> 1) * 32;
    const int wnBase = (wid & 1) * 64;

    f32x4 acc[MI][NI];
#pragma unroll
    for (int i = 0; i < MI; ++i)
#pragma unroll
        for (int j = 0; j < NI; ++j)
            acc[i][j] = (f32x4){0.f, 0.f, 0.f, 0.f};

#pragma unroll
    for (int ks = 0; ks < 4; ++ks) {
        const int kb = ks * 64 + ko * 16;
        bf16x8 a[MI], b[NI];
#pragma unroll
        for (int j = 0; j < NI; ++j) {
            int row = wnBase + j * 16 + lm;
            b[j] = *(const bf16x8*)(Wb + row * 256 + kb);   // direct global (L2-hot)
        }
#pragma unroll
        for (int i = 0; i < MI; ++i) {
            int row = wmBase + i * 16 + lm;
            a[i] = *(const bf16x8*)(Ac + row * 256 + (kb ^ ((row & 7) << 4)));
        }
#pragma unroll
        for (int i = 0; i < MI; ++i)
#pragma unroll
            for (int j = 0; j < NI; ++j)
                acc[i][j] = __builtin_amdgcn_mfma_f32_16x16x32_bf16(b[j], a[i], acc[i][j], 0, 0, 0);
    }

#pragma unroll
    for (int i = 0; i < MI; ++i) {
        const int node = m0 + wmBase + i * 16 + lm;
        if (node < N) {
#pragma unroll
            for (int j = 0; j < NI; ++j) {
                const int col0 = wnBase + j * 16 + ko * 4;
                const float4 bv = *(const float4*)&bias[col0];
                uint2 o;
                o.x = (unsigned int)f2b(acc[i][j][0] + bv.x) |
                      ((unsigned int)f2b(acc[i][j][1] + bv.y) << 16);
                o.y = (unsigned int)f2b(acc[i][j][2] + bv.z) |
                      ((unsigned int)f2b(acc[i][j][3] + bv.w) << 16);
                *(uint2*)&outb[(size_t)node * 128 + col0] = o;
            }
        }
    }
}

// ---------------- launch ----------------

extern "C" void kernel_launch(void* const* d_in, const int* in_sizes, int n_in,
                              void* d_out, int out_size, void* d_ws, size_t ws_size,
                              hipStream_t stream) {
    const float* x   = (const float*)d_in[0];
    const int*   ei  = (const int*)d_in[1];
    const float* Wl0 = (const float*)d_in[2];
    const float* Wr0 = (const float*)d_in[3];
    const float* b0  = (const float*)d_in[4];
    const float* Wl1 = (const float*)d_in[5];
    const float* Wr1 = (const float*)d_in[6];
    const float* b1  = (const float*)d_in[7];
    const float* Wl2 = (const float*)d_in[8];
    const float* Wr2 = (const float*)d_in[9];
    const float* b2  = (const float*)d_in[10];
    float* out = (float*)d_out;

    const int N = in_sizes[0] / NF;
    const int E = in_sizes[1] / 2;
    const int* srcv = ei;
    const int* dstv = ei + E;

    const int NB   = (N + 255) >> 8;
    const int NBLK = (E + CHUNK - 1) / CHUNK;
    const int T    = NB * NBLK;
    const int NS   = (T + 255) / 256;

    char* w = (char*)d_ws;
    auto alloc = [&](size_t bytes) {
        void* p = (void*)w;
        w += (bytes + 255) & ~(size_t)255;
        return p;
    };
    unsigned short* xb   = (unsigned short*)alloc((size_t)N * NF * 2);
    unsigned short* h1b  = (unsigned short*)alloc((size_t)N * NF * 2);
    unsigned short* h2b  = (unsigned short*)alloc((size_t)N * NF * 2);
    // fp8 region (25.6 MB): x8 + h18 while live; z2b aliases it afterwards
    unsigned char*  u8   = (unsigned char*)alloc((size_t)N * NF * 2);
    unsigned char*  x8   = u8;                       // [N][128] fp8
    unsigned char*  h18  = u8 + (size_t)N * NF;      // [N][128] fp8
    unsigned short* z2b  = (unsigned short*)u8;      // [N][128] bf16 (after x8/h18 dead)
    unsigned short* Wc0  = (unsigned short*)alloc((size_t)128 * 256 * 2);
    unsigned short* Wc1  = (unsigned short*)alloc((size_t)128 * 256 * 2);
    unsigned short* Wst2 = (unsigned short*)alloc((size_t)128 * 128 * 2);
    float*          bst2 = (float*)alloc((size_t)128 * 4);
    int*   offs   = (int*)alloc((size_t)(N + 1) * 4);
    int*   csr    = (int*)alloc((size_t)E * 4);
    float* rdeg   = (float*)alloc((size_t)N * 4);
    unsigned int* recs = (unsigned int*)alloc((size_t)E * 4);
    int*   hist   = (int*)alloc((size_t)T * 4);
    int*   base   = (int*)alloc((size_t)T * 4);
    int*   bstart = (int*)alloc((size_t)(NB + 1) * 4);
    int*   sb1    = (int*)alloc((size_t)1024 * 4);
    int*   sb2    = (int*)alloc((size_t)1024 * 4);

    const int n4 = N * NF / 4;
    const int bCvt = (n4 + 255) / 256;
    const int bW0  = bCvt + 64;            // wcat0: 16384/256
    const int bW1  = bW0 + 64;             // wcat1
    const int bWs  = bW1 + 32;             // wstack: 8192/256
    const int bTot = bWs + NBLK;           // + hist

    prep_kernel<<<bTot, 256, 0, stream>>>(x, xb, x8, n4,
                                          Wl0, Wr0, Wc0, Wl1, Wr1, Wc1,
                                          Wl2, Wr2, b2, Wst2, bst2,
                                          dstv, hist, E, NB,
                                          bCvt, bW0, bW1, bWs);
    sb_sum<<<NS, 256, 0, stream>>>(hist, sb1, T, NB, NBLK);
    sb_scan<<<1, 1024, 0, stream>>>(sb1, sb2, NS);
    sb_apply<<<NS, 256, 0, stream>>>(hist, sb2, base, bstart, T, NB, NBLK, E);
    scat_kernel<<<NBLK, 256, 0, stream>>>(srcv, dstv, base, recs, E, NB, NBLK);
    csr_kernel<<<NB, 256, 0, stream>>>(recs, bstart, offs, rdeg, csr, N, E);

    const int ab  = (N + 3) / 4;
    const int gb64 = (N + 63) / 64;

    // layer 0: fused gather(fp8 x) + GEMM; also emits fp8 h1 for next gather
    fused_layer<true><<<gb64, 256, 0, stream>>>(x8, xb, offs, csr, rdeg,
                                                Wc0, b0, h1b, h18, N);

    // layer 1: fused gather(fp8 h1) + GEMM
    fused_layer<false><<<gb64, 256, 0, stream>>>(h18, h1b, offs, csr, rdeg,
                                                 Wc1, b1, h2b, nullptr, N);

    // layer 2: transform-first (bf16), fused final agg
    gemmz_kernel<<<gb64, 256, 0, stream>>>(h2b, Wst2, bst2, z2b, N);
    agg2_kernel<<<ab, 256, 0, stream>>>(z2b, offs, csr, rdeg, out, N);
}

// Round 14
// 319.377 us; speedup vs baseline: 1.0833x; 1.0833x over previous
//
#include <hip/hip_runtime.h>

#define NF 128      // feature width for x / hidden layers
#define CHUNK 8192  // edges per block in CSR-build phase 1

typedef __attribute__((ext_vector_type(8))) short bf16x8;
typedef __attribute__((ext_vector_type(4))) float f32x4;
typedef __attribute__((ext_vector_type(2))) float f32x2;

__device__ __forceinline__ unsigned short f2b(float f) {
    unsigned int u = __float_as_uint(f);
    unsigned int r = (u + 0x7fffu + ((u >> 16) & 1u)) >> 16;  // round-nearest-even
    return (unsigned short)r;
}

// ========== fused prep: cvt(+fp8) | wcat0 | wcat1 | wstack | hist ============

__global__ __launch_bounds__(256) void prep_kernel(
        const float* __restrict__ x, unsigned short* __restrict__ xb,
        unsigned char* __restrict__ x8, int n4,
        const float* __restrict__ Wl0, const float* __restrict__ Wr0, unsigned short* __restrict__ Wc0,
        const float* __restrict__ Wl1, const float* __restrict__ Wr1, unsigned short* __restrict__ Wc1,
        const float* __restrict__ Wl2, const float* __restrict__ Wr2, const float* __restrict__ b2,
        unsigned short* __restrict__ Wst, float* __restrict__ bst,
        const int* __restrict__ dst, int* __restrict__ hist, int E, int NB,
        int bCvt, int bW0, int bW1, int bWs) {
    __shared__ int hsh[512];
    const int blk = blockIdx.x;
    const int tid = threadIdx.x;
    if (blk < bCvt) {
        int i = blk * 256 + tid;
        if (i < n4) {
            float4 v = *(const float4*)&x[(size_t)i * 4];
            uint2 o;
            o.x = (unsigned int)f2b(v.x) | ((unsigned int)f2b(v.y) << 16);
            o.y = (unsigned int)f2b(v.z) | ((unsigned int)f2b(v.w) << 16);
            *(uint2*)&xb[(size_t)i * 4] = o;
            unsigned p = __builtin_amdgcn_cvt_pk_fp8_f32(v.x, v.y, 0, false);
            p = __builtin_amdgcn_cvt_pk_fp8_f32(v.z, v.w, p, true);
            *(unsigned int*)&x8[(size_t)i * 4] = p;
        }
    } else if (blk < bW1) {
        const bool first = blk < bW0;
        int i = (blk - (first ? bCvt : bW0)) * 256 + tid;  // < 16384
        const float* Wl = first ? Wl0 : Wl1;
        const float* Wr = first ? Wr0 : Wr1;
        unsigned short* Wc = first ? Wc0 : Wc1;
        int f = i >> 7, k = i & 127;
        Wc[f * 256 + k] = f2b(Wl[i]);
        Wc[f * 256 + 128 + k] = f2b(Wr[i]);
    } else if (blk < bWs) {
        int i = (blk - bW1) * 256 + tid;  // < 8192
        int f = i >> 7, k = i & 127;
        Wst[f * 128 + k] = f2b(Wl2[i]);
        Wst[(f + 64) * 128 + k] = f2b(Wr2[i]);
        if (k == 0) {
            bst[f] = 0.f;
            bst[f + 64] = b2[f];
        }
    } else {
        const int hb = blk - bWs;  // hist block
        for (int i = tid; i < NB; i += 256) hsh[i] = 0;
        __syncthreads();
        const int e0 = hb * CHUNK;
        for (int i = tid; i < CHUNK; i += 256) {
            int e = e0 + i;
            if (e < E) atomicAdd(&hsh[dst[e] >> 8], 1);
        }
        __syncthreads();
        for (int i = tid; i < NB; i += 256) hist[hb * NB + i] = hsh[i];
    }
}

// ================= CSR build scan chain =================

__global__ __launch_bounds__(256) void sb_sum(const int* __restrict__ hist,
                                              int* __restrict__ bsum,
                                              int T, int NB, int NBLK) {
    int i = blockIdx.x * 256 + threadIdx.x;
    int v = 0;
    if (i < T) {
        int b = i / NBLK, blk = i - b * NBLK;
        v = hist[blk * NB + b];
    }
#pragma unroll
    for (int d = 32; d; d >>= 1) v += __shfl_down(v, d, 64);
    __shared__ int wsum[4];
    if ((threadIdx.x & 63) == 0) wsum[threadIdx.x >> 6] = v;
    __syncthreads();
    if (threadIdx.x == 0) bsum[blockIdx.x] = wsum[0] + wsum[1] + wsum[2] + wsum[3];
}

__global__ __launch_bounds__(1024) void sb_scan(const int* __restrict__ bsum,
                                                int* __restrict__ bpre, int NS) {
    __shared__ int s[1024];
    int t = threadIdx.x;
    int v = (t < NS) ? bsum[t] : 0;
    s[t] = v;
    __syncthreads();
    for (int d = 1; d < 1024; d <<= 1) {
        int u = (t >= d) ? s[t - d] : 0;
        __syncthreads();
        s[t] += u;
        __syncthreads();
    }
    if (t < NS) bpre[t] = s[t] - v;
}

__global__ __launch_bounds__(256) void sb_apply(const int* __restrict__ hist,
                                                const int* __restrict__ bpre,
                                                int* __restrict__ base,
                                                int* __restrict__ bstart,
                                                int T, int NB, int NBLK, int E) {
    __shared__ int s[256];
    int i = blockIdx.x * 256 + threadIdx.x;
    int t = threadIdx.x;
    int v = 0;
    int b = 0, blk = 0;
    if (i < T) {
        b = i / NBLK;
        blk = i - b * NBLK;
        v = hist[blk * NB + b];
    }
    s[t] = v;
    __syncthreads();
    for (int d = 1; d < 256; d <<= 1) {
        int u = (t >= d) ? s[t - d] : 0;
        __syncthreads();
        s[t] += u;
        __syncthreads();
    }
    if (i < T) {
        int val = bpre[blockIdx.x] + s[t] - v;
        base[i] = val;
        if (blk == 0) bstart[b] = val;
        if (i == 0) bstart[NB] = E;
    }
}

__global__ __launch_bounds__(256) void scat_kernel(const int* __restrict__ src,
                                                   const int* __restrict__ dst,
                                                   const int* __restrict__ base,
                                                   unsigned int* __restrict__ recs,
                                                   int E, int NB, int NBLK) {
    __shared__ int cur[512];
    const int blk = blockIdx.x;
    for (int b = threadIdx.x; b < NB; b += 256) cur[b] = base[b * NBLK + blk];
    __syncthreads();
    const int e0 = blk * CHUNK;
    for (int i = threadIdx.x; i < CHUNK; i += 256) {
        int e = e0 + i;
        if (e >= E) continue;
        int d = dst[e];
        int b = d >> 8;
        int pos = atomicAdd(&cur[b], 1);
        recs[pos] = (unsigned int)src[e] | ((unsigned int)(d & 255) << 24);
    }
}

__global__ __launch_bounds__(256) void csr_kernel(const unsigned int* __restrict__ recs,
                                                  const int* __restrict__ bstart,
                                                  int* __restrict__ offs,
                                                  float* __restrict__ rdeg,
                                                  int* __restrict__ csr,
                                                  int N, int E) {
    __shared__ int cnt[256];
    __shared__ int sc[256];
    __shared__ int cur[256];
    const int b = blockIdx.x;
    const int t = threadIdx.x;
    const int s0 = bstart[b], s1 = bstart[b + 1];
    cnt[t] = 0;
    __syncthreads();
    for (int i = s0 + t; i < s1; i += 256) atomicAdd(&cnt[recs[i] >> 24], 1);
    __syncthreads();
    int v = cnt[t];
    sc[t] = v;
    __syncthreads();
    for (int d = 1; d < 256; d <<= 1) {
        int u = (t >= d) ? sc[t - d] : 0;
        __syncthreads();
        sc[t] += u;
        __syncthreads();
    }
    int excl = sc[t] - v;
    int node = b * 256 + t;
    if (node < N) {
        offs[node] = s0 + excl;
        rdeg[node] = 1.0f / (float)(v > 1 ? v : 1);
        if (node == N - 1) offs[N] = E;
    }
    cur[t] = s0 + excl;
    __syncthreads();
    for (int i = s0 + t; i < s1; i += 256) {
        unsigned int r = recs[i];
        int pos = atomicAdd(&cur[r >> 24], 1);
        csr[pos] = (int)(r & 0xFFFFFFu);
    }
}

// -------- mean aggregation from FP8 rows (128B/row), bf16 mean out -----------
// One node/wave; exact binary-decomposed edge groups (no wasted loads).

__global__ __launch_bounds__(256) void agg8_kernel(
        const unsigned char* __restrict__ h8, const int* __restrict__ offs,
        const int* __restrict__ csr, const float* __restrict__ rdeg,
        unsigned short* __restrict__ meanout, int N) {
    const int node = blockIdx.x * 4 + (threadIdx.x >> 6);
    const int lane = threadIdx.x & 63;
    if (node >= N) return;
    const int s0 = offs[node], s1 = offs[node + 1];
    const char* __restrict__ hb = (const char*)h8;
    const unsigned lane2 = (unsigned)lane * 2u;
    f32x2 acc = {0.f, 0.f};
    for (int base = s0; base < s1; base += 64) {
        const int cnt = min(64, s1 - base);
        const int boff = csr[base + min(lane, cnt - 1)] << 7;  // fp8 row byte offset
        int j = 0;
#define AGG8_GROUP(NG)                                                         \
        {                                                                      \
            unsigned o[NG];                                                    \
            _Pragma("unroll")                                                  \
            for (int k = 0; k < NG; ++k)                                       \
                o[k] = (unsigned)__shfl(boff, j + k, 64) + lane2;              \
            unsigned int v[NG];                                                \
            _Pragma("unroll")                                                  \
            for (int k = 0; k < NG; ++k)                                       \
                v[k] = *(const unsigned short*)(hb + o[k]);                    \
            _Pragma("unroll")                                                  \
            for (int k = 0; k < NG; ++k)                                       \
                acc += __builtin_amdgcn_cvt_pk_f32_fp8(v[k], false);           \
            j += NG;                                                           \
        }
        while (j + 16 <= cnt) AGG8_GROUP(16)
        if (cnt & 8) AGG8_GROUP(8)
        if (cnt & 4) AGG8_GROUP(4)
        if (cnt & 2) AGG8_GROUP(2)
        if (cnt & 1) AGG8_GROUP(1)
#undef AGG8_GROUP
    }
    float r = rdeg[node];
    unsigned int o = (unsigned int)f2b(acc.x * r) | ((unsigned int)f2b(acc.y * r) << 16);
    *(unsigned int*)&meanout[(size_t)node * NF + lane * 2] = o;
}

// ---- layer-2 final agg: out[i] = mean_j zl[j] + zr[i]  (fp32 out) -----------
// One node/wave; feature == lane (64 features); single-segment 128B row loads.

__global__ __launch_bounds__(256) void agg2_kernel(
        const unsigned short* __restrict__ z, const int* __restrict__ offs,
        const int* __restrict__ csr, const float* __restrict__ rdeg,
        float* __restrict__ out, int N) {
    const int node = blockIdx.x * 4 + (threadIdx.x >> 6);
    const int lane = threadIdx.x & 63;
    if (node >= N) return;
    const int s0 = offs[node], s1 = offs[node + 1];
    const char* __restrict__ zb = (const char*)z;
    const unsigned lane2 = (unsigned)lane * 2u;
    float acc = 0.f;
    for (int base = s0; base < s1; base += 64) {
        const int cnt = min(64, s1 - base);
        const int boff = csr[base + min(lane, cnt - 1)] << 8;  // zl = first 128B of 256B row
        int j = 0;
#define AGG2_GROUP(NG)                                                         \
        {                                                                      \
            unsigned o[NG];                                                    \
            _Pragma("unroll")                                                  \
            for (int k = 0; k < NG; ++k)                                       \
                o[k] = (unsigned)__shfl(boff, j + k, 64) + lane2;              \
            unsigned int v[NG];                                                \
            _Pragma("unroll")                                                  \
            for (int k = 0; k < NG; ++k)                                       \
                v[k] = *(const unsigned short*)(zb + o[k]);                    \
            _Pragma("unroll")                                                  \
            for (int k = 0; k < NG; ++k)                                       \
                acc += __uint_as_float(v[k] << 16);                            \
            j += NG;                                                           \
        }
        while (j + 16 <= cnt) AGG2_GROUP(16)
        if (cnt & 8) AGG2_GROUP(8)
        if (cnt & 4) AGG2_GROUP(4)
        if (cnt & 2) AGG2_GROUP(2)
        if (cnt & 1) AGG2_GROUP(1)
#undef AGG2_GROUP
    }
    float r = rdeg[node];
    unsigned int vr = *(const unsigned short*)(zb + (size_t)node * 256 + 128 + lane2);
    out[(size_t)node * 64 + lane] = acc * r + __uint_as_float(vr << 16);
}

// ------- MFMA GEMM (layers 0/1): out = [mean|h] @ Wcat^T + b, relu, bf16 out ---
// NO LDS, NO BARRIER: A fragments and W read direct from global (A rows unique
// per lane-slot; consecutive ks walk the same rows -> L1-resident; W L2-hot).
// Occupancy limited only by VGPR -> streaming k-loop, latency hidden by TLP.

template <bool OUT8>
__global__ __launch_bounds__(256) void gemm_kernel(
        const unsigned short* __restrict__ Abuf,   // mean [N][128] bf16
        const unsigned short* __restrict__ Hbuf,   // root [N][128] bf16
        const unsigned short* __restrict__ Wcat,   // [128][256] bf16
        const float* __restrict__ bias,            // [128] fp32
        unsigned short* __restrict__ outb,
        unsigned char* __restrict__ out8,
        int N) {
    const int tid = threadIdx.x, wid = tid >> 6, lane = tid & 63;
    const int m0 = blockIdx.x * 128;
    const int lm = lane & 15, ko = lane >> 4;
    const int wmBase = (wid >> 1) * 64;
    const int wnBase = (wid & 1) * 64;
    const char* __restrict__ Ab = (const char*)Abuf;
    const char* __restrict__ Hb = (const char*)Hbuf;
    const char* __restrict__ Wb = (const char*)Wcat;

    constexpr int MI = 4;
    constexpr int NI = 4;

    // A-fragment rows (clamped; garbage rows masked at store)
    size_t arow[MI];
#pragma unroll
    for (int i = 0; i < MI; ++i)
        arow[i] = (size_t)min(m0 + wmBase + i * 16 + lm, N - 1) * 256;
    const size_t wrow[NI] = {
        (size_t)(wnBase + 0 * 16 + lm) * 512, (size_t)(wnBase + 1 * 16 + lm) * 512,
        (size_t)(wnBase + 2 * 16 + lm) * 512, (size_t)(wnBase + 3 * 16 + lm) * 512};

    f32x4 acc[MI][NI];
#pragma unroll
    for (int i = 0; i < MI; ++i)
#pragma unroll
        for (int j = 0; j < NI; ++j)
            acc[i][j] = (f32x4){0.f, 0.f, 0.f, 0.f};

#pragma unroll
    for (int ks = 0; ks < 8; ++ks) {
        const int kb = ks * 64 + ko * 16;       // 0..511 over [mean|root]
        const int kbl = kb & 255;
        const char* __restrict__ Abase = (ks < 4) ? Ab : Hb;
        bf16x8 a[MI], b[NI];
#pragma unroll
        for (int j = 0; j < NI; ++j)
            b[j] = *(const bf16x8*)(Wb + wrow[j] + kb);
#pragma unroll
        for (int i = 0; i < MI; ++i)
            a[i] = *(const bf16x8*)(Abase + arow[i] + kbl);
#pragma unroll
        for (int i = 0; i < MI; ++i)
#pragma unroll
            for (int j = 0; j < NI; ++j)
                acc[i][j] = __builtin_amdgcn_mfma_f32_16x16x32_bf16(b[j], a[i], acc[i][j], 0, 0, 0);
    }

#pragma unroll
    for (int i = 0; i < MI; ++i) {
        const int node = m0 + wmBase + i * 16 + lm;
        if (node < N) {
#pragma unroll
            for (int j = 0; j < NI; ++j) {
                const int col0 = wnBase + j * 16 + ko * 4;
                const float4 bv = *(const float4*)&bias[col0];
                float v0 = fmaxf(acc[i][j][0] + bv.x, 0.f);
                float v1 = fmaxf(acc[i][j][1] + bv.y, 0.f);
                float v2 = fmaxf(acc[i][j][2] + bv.z, 0.f);
                float v3 = fmaxf(acc[i][j][3] + bv.w, 0.f);
                uint2 o;
                o.x = (unsigned int)f2b(v0) | ((unsigned int)f2b(v1) << 16);
                o.y = (unsigned int)f2b(v2) | ((unsigned int)f2b(v3) << 16);
                *(uint2*)&outb[(size_t)node * 128 + col0] = o;
                if (OUT8) {
                    unsigned p = __builtin_amdgcn_cvt_pk_fp8_f32(v0, v1, 0, false);
                    p = __builtin_amdgcn_cvt_pk_fp8_f32(v2, v3, p, true);
                    *(unsigned int*)&out8[(size_t)node * 128 + col0] = p;
                }
            }
        }
    }
}

// ---------- MFMA GEMM (layer 2): z = h @ Wst^T + bst  (K=128, bf16 out) -------
// Same no-LDS streaming structure.

__global__ __launch_bounds__(256) void gemmz_kernel(
        const unsigned short* __restrict__ A,    // [N][128] bf16
        const unsigned short* __restrict__ W,    // [128][128] bf16
        const float* __restrict__ bias,          // [128] fp32
        unsigned short* __restrict__ outb,       // [N][128] bf16
        int N) {
    const int tid = threadIdx.x, wid = tid >> 6, lane = tid & 63;
    const int m0 = blockIdx.x * 128;
    const int lm = lane & 15, ko = lane >> 4;
    const int wmBase = (wid >> 1) * 64;
    const int wnBase = (wid & 1) * 64;
    const char* __restrict__ Ab = (const char*)A;
    const char* __restrict__ Wb = (const char*)W;

    size_t arow[4];
#pragma unroll
    for (int i = 0; i < 4; ++i)
        arow[i] = (size_t)min(m0 + wmBase + i * 16 + lm, N - 1) * 256;
    const size_t wrow[4] = {
        (size_t)(wnBase + 0 * 16 + lm) * 256, (size_t)(wnBase + 1 * 16 + lm) * 256,
        (size_t)(wnBase + 2 * 16 + lm) * 256, (size_t)(wnBase + 3 * 16 + lm) * 256};

    f32x4 acc[4][4];
#pragma unroll
    for (int i = 0; i < 4; ++i)
#pragma unroll
        for (int j = 0; j < 4; ++j)
            acc[i][j] = (f32x4){0.f, 0.f, 0.f, 0.f};

#pragma unroll
    for (int ks = 0; ks < 4; ++ks) {
        const int kb = ks * 64 + ko * 16;
        bf16x8 a[4], b[4];
#pragma unroll
        for (int j = 0; j < 4; ++j)
            b[j] = *(const bf16x8*)(Wb + wrow[j] + kb);
#pragma unroll
        for (int i = 0; i < 4; ++i)
            a[i] = *(const bf16x8*)(Ab + arow[i] + kb);
#pragma unroll
        for (int i = 0; i < 4; ++i)
#pragma unroll
            for (int j = 0; j < 4; ++j)
                acc[i][j] = __builtin_amdgcn_mfma_f32_16x16x32_bf16(b[j], a[i], acc[i][j], 0, 0, 0);
    }

#pragma unroll
    for (int i = 0; i < 4; ++i) {
        const int node = m0 + wmBase + i * 16 + lm;
        if (node < N) {
#pragma unroll
            for (int j = 0; j < 4; ++j) {
                const int col0 = wnBase + j * 16 + ko * 4;
                const float4 bv = *(const float4*)&bias[col0];
                uint2 o;
                o.x = (unsigned int)f2b(acc[i][j][0] + bv.x) |
                      ((unsigned int)f2b(acc[i][j][1] + bv.y) << 16);
                o.y = (unsigned int)f2b(acc[i][j][2] + bv.z) |
                      ((unsigned int)f2b(acc[i][j][3] + bv.w) << 16);
                *(uint2*)&outb[(size_t)node * 128 + col0] = o;
            }
        }
    }
}

// ---------------- launch ----------------

extern "C" void kernel_launch(void* const* d_in, const int* in_sizes, int n_in,
                              void* d_out, int out_size, void* d_ws, size_t ws_size,
                              hipStream_t stream) {
    const float* x   = (const float*)d_in[0];
    const int*   ei  = (const int*)d_in[1];
    const float* Wl0 = (const float*)d_in[2];
    const float* Wr0 = (const float*)d_in[3];
    const float* b0  = (const float*)d_in[4];
    const float* Wl1 = (const float*)d_in[5];
    const float* Wr1 = (const float*)d_in[6];
    const float* b1  = (const float*)d_in[7];
    const float* Wl2 = (const float*)d_in[8];
    const float* Wr2 = (const float*)d_in[9];
    const float* b2  = (const float*)d_in[10];
    float* out = (float*)d_out;

    const int N = in_sizes[0] / NF;
    const int E = in_sizes[1] / 2;
    const int* srcv = ei;
    const int* dstv = ei + E;

    const int NB   = (N + 255) >> 8;
    const int NBLK = (E + CHUNK - 1) / CHUNK;
    const int T    = NB * NBLK;
    const int NS   = (T + 255) / 256;

    char* w = (char*)d_ws;
    auto alloc = [&](size_t bytes) {
        void* p = (void*)w;
        w += (bytes + 255) & ~(size_t)255;
        return p;
    };
    unsigned short* xb   = (unsigned short*)alloc((size_t)N * NF * 2);
    unsigned short* h1b  = (unsigned short*)alloc((size_t)N * NF * 2);
    unsigned short* h2b  = (unsigned short*)alloc((size_t)N * NF * 2);
    unsigned short* mb   = (unsigned short*)alloc((size_t)N * NF * 2);
    // fp8 region (25.6 MB): x8 + h18 while live; z2b aliases it afterwards
    unsigned char*  u8   = (unsigned char*)alloc((size_t)N * NF * 2);
    unsigned char*  x8   = u8;                       // [N][128] fp8
    unsigned char*  h18  = u8 + (size_t)N * NF;      // [N][128] fp8
    unsigned short* z2b  = (unsigned short*)u8;      // [N][128] bf16 (after x8/h18 dead)
    unsigned short* Wc0  = (unsigned short*)alloc((size_t)128 * 256 * 2);
    unsigned short* Wc1  = (unsigned short*)alloc((size_t)128 * 256 * 2);
    unsigned short* Wst2 = (unsigned short*)alloc((size_t)128 * 128 * 2);
    float*          bst2 = (float*)alloc((size_t)128 * 4);
    int*   offs   = (int*)alloc((size_t)(N + 1) * 4);
    int*   csr    = (int*)alloc((size_t)E * 4);
    float* rdeg   = (float*)alloc((size_t)N * 4);
    unsigned int* recs = (unsigned int*)alloc((size_t)E * 4);
    int*   hist   = (int*)alloc((size_t)T * 4);
    int*   base   = (int*)alloc((size_t)T * 4);
    int*   bstart = (int*)alloc((size_t)(NB + 1) * 4);
    int*   sb1    = (int*)alloc((size_t)1024 * 4);
    int*   sb2    = (int*)alloc((size_t)1024 * 4);

    const int n4 = N * NF / 4;
    const int bCvt = (n4 + 255) / 256;
    const int bW0  = bCvt + 64;            // wcat0: 16384/256
    const int bW1  = bW0 + 64;             // wcat1
    const int bWs  = bW1 + 32;             // wstack: 8192/256
    const int bTot = bWs + NBLK;           // + hist

    prep_kernel<<<bTot, 256, 0, stream>>>(x, xb, x8, n4,
                                          Wl0, Wr0, Wc0, Wl1, Wr1, Wc1,
                                          Wl2, Wr2, b2, Wst2, bst2,
                                          dstv, hist, E, NB,
                                          bCvt, bW0, bW1, bWs);
    sb_sum<<<NS, 256, 0, stream>>>(hist, sb1, T, NB, NBLK);
    sb_scan<<<1, 1024, 0, stream>>>(sb1, sb2, NS);
    sb_apply<<<NS, 256, 0, stream>>>(hist, sb2, base, bstart, T, NB, NBLK, E);
    scat_kernel<<<NBLK, 256, 0, stream>>>(srcv, dstv, base, recs, E, NB, NBLK);
    csr_kernel<<<NB, 256, 0, stream>>>(recs, bstart, offs, rdeg, csr, N, E);

    const int ab  = (N + 3) / 4;
    const int gb  = (N + 127) / 128;

    // layer 0: mean from fp8 x; gemm also emits fp8 h1 for next gather
    agg8_kernel<<<ab, 256, 0, stream>>>(x8, offs, csr, rdeg, mb, N);
    gemm_kernel<true><<<gb, 256, 0, stream>>>(mb, xb, Wc0, b0, h1b, h18, N);

    // layer 1: mean from fp8 h1, root bf16 h1
    agg8_kernel<<<ab, 256, 0, stream>>>(h18, offs, csr, rdeg, mb, N);
    gemm_kernel<false><<<gb, 256, 0, stream>>>(mb, h1b, Wc1, b1, h2b, nullptr, N);

    // layer 2: transform-first (bf16), fused final agg
    gemmz_kernel<<<gb, 256, 0, stream>>>(h2b, Wst2, bst2, z2b, N);
    agg2_kernel<<<ab, 256, 0, stream>>>(z2b, offs, csr, rdeg, out, N);
}

// Round 15
// 278.929 us; speedup vs baseline: 1.2404x; 1.1450x over previous
//
#include <hip/hip_runtime.h>

#define NF 128      // feature width for x / hidden layers
#define CHUNK 8192  // edges per block in CSR-build phase 1

typedef __attribute__((ext_vector_type(8))) short bf16x8;
typedef __attribute__((ext_vector_type(4))) float f32x4;
typedef __attribute__((ext_vector_type(2))) float f32x2;

__device__ __forceinline__ unsigned short f2b(float f) {
    unsigned int u = __float_as_uint(f);
    unsigned int r = (u + 0x7fffu + ((u >> 16) & 1u)) >> 16;  // round-nearest-even
    return (unsigned short)r;
}

// async global->LDS, 16B per lane. LDS dest = wave-uniform base (+lane*16 by HW);
// global src is per-lane.
__device__ __forceinline__ void gld_lds16(const void* g, const void* l) {
    __builtin_amdgcn_global_load_lds(
        (const __attribute__((address_space(1))) unsigned int*)(unsigned long long)g,
        (__attribute__((address_space(3))) unsigned int*)(unsigned int)(unsigned long long)l,
        16, 0, 0);
}

// ========== fused prep: cvt(+fp8) | wcat0 | wcat1 | wstack | hist ============

__global__ __launch_bounds__(256) void prep_kernel(
        const float* __restrict__ x, unsigned short* __restrict__ xb,
        unsigned char* __restrict__ x8, int n4,
        const float* __restrict__ Wl0, const float* __restrict__ Wr0, unsigned short* __restrict__ Wc0,
        const float* __restrict__ Wl1, const float* __restrict__ Wr1, unsigned short* __restrict__ Wc1,
        const float* __restrict__ Wl2, const float* __restrict__ Wr2, const float* __restrict__ b2,
        unsigned short* __restrict__ Wst, float* __restrict__ bst,
        const int* __restrict__ dst, int* __restrict__ hist, int E, int NB,
        int bCvt, int bW0, int bW1, int bWs) {
    __shared__ int hsh[512];
    const int blk = blockIdx.x;
    const int tid = threadIdx.x;
    if (blk < bCvt) {
        int i = blk * 256 + tid;
        if (i < n4) {
            float4 v = *(const float4*)&x[(size_t)i * 4];
            uint2 o;
            o.x = (unsigned int)f2b(v.x) | ((unsigned int)f2b(v.y) << 16);
            o.y = (unsigned int)f2b(v.z) | ((unsigned int)f2b(v.w) << 16);
            *(uint2*)&xb[(size_t)i * 4] = o;
            unsigned p = __builtin_amdgcn_cvt_pk_fp8_f32(v.x, v.y, 0, false);
            p = __builtin_amdgcn_cvt_pk_fp8_f32(v.z, v.w, p, true);
            *(unsigned int*)&x8[(size_t)i * 4] = p;
        }
    } else if (blk < bW1) {
        const bool first = blk < bW0;
        int i = (blk - (first ? bCvt : bW0)) * 256 + tid;  // < 16384
        const float* Wl = first ? Wl0 : Wl1;
        const float* Wr = first ? Wr0 : Wr1;
        unsigned short* Wc = first ? Wc0 : Wc1;
        int f = i >> 7, k = i & 127;
        Wc[f * 256 + k] = f2b(Wl[i]);
        Wc[f * 256 + 128 + k] = f2b(Wr[i]);
    } else if (blk < bWs) {
        int i = (blk - bW1) * 256 + tid;  // < 8192
        int f = i >> 7, k = i & 127;
        Wst[f * 128 + k] = f2b(Wl2[i]);
        Wst[(f + 64) * 128 + k] = f2b(Wr2[i]);
        if (k == 0) {
            bst[f] = 0.f;
            bst[f + 64] = b2[f];
        }
    } else {
        const int hb = blk - bWs;  // hist block
        for (int i = tid; i < NB; i += 256) hsh[i] = 0;
        __syncthreads();
        const int e0 = hb * CHUNK;
        for (int i = tid; i < CHUNK; i += 256) {
            int e = e0 + i;
            if (e < E) atomicAdd(&hsh[dst[e] >> 8], 1);
        }
        __syncthreads();
        for (int i = tid; i < NB; i += 256) hist[hb * NB + i] = hsh[i];
    }
}

// ================= CSR build scan chain =================

__global__ __launch_bounds__(256) void sb_sum(const int* __restrict__ hist,
                                              int* __restrict__ bsum,
                                              int T, int NB, int NBLK) {
    int i = blockIdx.x * 256 + threadIdx.x;
    int v = 0;
    if (i < T) {
        int b = i / NBLK, blk = i - b * NBLK;
        v = hist[blk * NB + b];
    }
#pragma unroll
    for (int d = 32; d; d >>= 1) v += __shfl_down(v, d, 64);
    __shared__ int wsum[4];
    if ((threadIdx.x & 63) == 0) wsum[threadIdx.x >> 6] = v;
    __syncthreads();
    if (threadIdx.x == 0) bsum[blockIdx.x] = wsum[0] + wsum[1] + wsum[2] + wsum[3];
}

__global__ __launch_bounds__(1024) void sb_scan(const int* __restrict__ bsum,
                                                int* __restrict__ bpre, int NS) {
    __shared__ int s[1024];
    int t = threadIdx.x;
    int v = (t < NS) ? bsum[t] : 0;
    s[t] = v;
    __syncthreads();
    for (int d = 1; d < 1024; d <<= 1) {
        int u = (t >= d) ? s[t - d] : 0;
        __syncthreads();
        s[t] += u;
        __syncthreads();
    }
    if (t < NS) bpre[t] = s[t] - v;
}

__global__ __launch_bounds__(256) void sb_apply(const int* __restrict__ hist,
                                                const int* __restrict__ bpre,
                                                int* __restrict__ base,
                                                int* __restrict__ bstart,
                                                int T, int NB, int NBLK, int E) {
    __shared__ int s[256];
    int i = blockIdx.x * 256 + threadIdx.x;
    int t = threadIdx.x;
    int v = 0;
    int b = 0, blk = 0;
    if (i < T) {
        b = i / NBLK;
        blk = i - b * NBLK;
        v = hist[blk * NB + b];
    }
    s[t] = v;
    __syncthreads();
    for (int d = 1; d < 256; d <<= 1) {
        int u = (t >= d) ? s[t - d] : 0;
        __syncthreads();
        s[t] += u;
        __syncthreads();
    }
    if (i < T) {
        int val = bpre[blockIdx.x] + s[t] - v;
        base[i] = val;
        if (blk == 0) bstart[b] = val;
        if (i == 0) bstart[NB] = E;
    }
}

__global__ __launch_bounds__(256) void scat_kernel(const int* __restrict__ src,
                                                   const int* __restrict__ dst,
                                                   const int* __restrict__ base,
                                                   unsigned int* __restrict__ recs,
                                                   int E, int NB, int NBLK) {
    __shared__ int cur[512];
    const int blk = blockIdx.x;
    for (int b = threadIdx.x; b < NB; b += 256) cur[b] = base[b * NBLK + blk];
    __syncthreads();
    const int e0 = blk * CHUNK;
    for (int i = threadIdx.x; i < CHUNK; i += 256) {
        int e = e0 + i;
        if (e >= E) continue;
        int d = dst[e];
        int b = d >> 8;
        int pos = atomicAdd(&cur[b], 1);
        recs[pos] = (unsigned int)src[e] | ((unsigned int)(d & 255) << 24);
    }
}

__global__ __launch_bounds__(256) void csr_kernel(const unsigned int* __restrict__ recs,
                                                  const int* __restrict__ bstart,
                                                  int* __restrict__ offs,
                                                  float* __restrict__ rdeg,
                                                  int* __restrict__ csr,
                                                  int N, int E) {
    __shared__ int cnt[256];
    __shared__ int sc[256];
    __shared__ int cur[256];
    const int b = blockIdx.x;
    const int t = threadIdx.x;
    const int s0 = bstart[b], s1 = bstart[b + 1];
    cnt[t] = 0;
    __syncthreads();
    for (int i = s0 + t; i < s1; i += 256) atomicAdd(&cnt[recs[i] >> 24], 1);
    __syncthreads();
    int v = cnt[t];
    sc[t] = v;
    __syncthreads();
    for (int d = 1; d < 256; d <<= 1) {
        int u = (t >= d) ? sc[t - d] : 0;
        __syncthreads();
        sc[t] += u;
        __syncthreads();
    }
    int excl = sc[t] - v;
    int node = b * 256 + t;
    if (node < N) {
        offs[node] = s0 + excl;
        rdeg[node] = 1.0f / (float)(v > 1 ? v : 1);
        if (node == N - 1) offs[N] = E;
    }
    cur[t] = s0 + excl;
    __syncthreads();
    for (int i = s0 + t; i < s1; i += 256) {
        unsigned int r = recs[i];
        int pos = atomicAdd(&cur[r >> 24], 1);
        csr[pos] = (int)(r & 0xFFFFFFu);
    }
}

// -------- mean aggregation from FP8 rows (128B/row), bf16 mean out -----------

__global__ __launch_bounds__(256) void agg8_kernel(
        const unsigned char* __restrict__ h8, const int* __restrict__ offs,
        const int* __restrict__ csr, const float* __restrict__ rdeg,
        unsigned short* __restrict__ meanout, int N) {
    const int node = blockIdx.x * 4 + (threadIdx.x >> 6);
    const int lane = threadIdx.x & 63;
    if (node >= N) return;
    const int s0 = offs[node], s1 = offs[node + 1];
    const char* __restrict__ hb = (const char*)h8;
    const unsigned lane2 = (unsigned)lane * 2u;
    f32x2 acc = {0.f, 0.f};
    for (int base = s0; base < s1; base += 64) {
        const int cnt = min(64, s1 - base);
        const int boff = csr[base + min(lane, cnt - 1)] << 7;  // fp8 row byte offset
        int j = 0;
#define AGG8_GROUP(NG)                                                         \
        {                                                                      \
            unsigned o[NG];                                                    \
            _Pragma("unroll")                                                  \
            for (int k = 0; k < NG; ++k)                                       \
                o[k] = (unsigned)__shfl(boff, j + k, 64) + lane2;              \
            unsigned int v[NG];                                                \
            _Pragma("unroll")                                                  \
            for (int k = 0; k < NG; ++k)                                       \
                v[k] = *(const unsigned short*)(hb + o[k]);                    \
            _Pragma("unroll")                                                  \
            for (int k = 0; k < NG; ++k)                                       \
                acc += __builtin_amdgcn_cvt_pk_f32_fp8(v[k], false);           \
            j += NG;                                                           \
        }
        while (j + 16 <= cnt) AGG8_GROUP(16)
        if (cnt & 8) AGG8_GROUP(8)
        if (cnt & 4) AGG8_GROUP(4)
        if (cnt & 2) AGG8_GROUP(2)
        if (cnt & 1) AGG8_GROUP(1)
#undef AGG8_GROUP
    }
    float r = rdeg[node];
    unsigned int o = (unsigned int)f2b(acc.x * r) | ((unsigned int)f2b(acc.y * r) << 16);
    *(unsigned int*)&meanout[(size_t)node * NF + lane * 2] = o;
}

// ---- layer-2 final agg: out[i] = mean_j zl[j] + zr[i]  (fp32 out) -----------

__global__ __launch_bounds__(256) void agg2_kernel(
        const unsigned short* __restrict__ z, const int* __restrict__ offs,
        const int* __restrict__ csr, const float* __restrict__ rdeg,
        float* __restrict__ out, int N) {
    const int node = blockIdx.x * 4 + (threadIdx.x >> 6);
    const int lane = threadIdx.x & 63;
    if (node >= N) return;
    const int s0 = offs[node], s1 = offs[node + 1];
    const char* __restrict__ zb = (const char*)z;
    const unsigned lane2 = (unsigned)lane * 2u;
    float acc = 0.f;
    for (int base = s0; base < s1; base += 64) {
        const int cnt = min(64, s1 - base);
        const int boff = csr[base + min(lane, cnt - 1)] << 8;  // zl = first 128B of 256B row
        int j = 0;
#define AGG2_GROUP(NG)                                                         \
        {                                                                      \
            unsigned o[NG];                                                    \
            _Pragma("unroll")                                                  \
            for (int k = 0; k < NG; ++k)                                       \
                o[k] = (unsigned)__shfl(boff, j + k, 64) + lane2;              \
            unsigned int v[NG];                                                \
            _Pragma("unroll")                                                  \
            for (int k = 0; k < NG; ++k)                                       \
                v[k] = *(const unsigned short*)(zb + o[k]);                    \
            _Pragma("unroll")                                                  \
            for (int k = 0; k < NG; ++k)                                       \
                acc += __uint_as_float(v[k] << 16);                            \
            j += NG;                                                           \
        }
        while (j + 16 <= cnt) AGG2_GROUP(16)
        if (cnt & 8) AGG2_GROUP(8)
        if (cnt & 4) AGG2_GROUP(4)
        if (cnt & 2) AGG2_GROUP(2)
        if (cnt & 1) AGG2_GROUP(1)
#undef AGG2_GROUP
    }
    float r = rdeg[node];
    unsigned int vr = *(const unsigned short*)(zb + (size_t)node * 256 + 128 + lane2);
    out[(size_t)node * 64 + lane] = acc * r + __uint_as_float(vr << 16);
}

// ------- MFMA GEMM (layers 0/1): out = [mean|h] @ Wcat^T + b, relu, bf16 out ---
// A staged in LDS (gld_lds16, pre-swizzled src); W direct-global (L2-hot).
// NEW: LDS-transposed epilogue -> fully coalesced uint4 stores (bf16 + fp8).

template <bool OUT8>
__global__ __launch_bounds__(256) void gemm_kernel(
        const unsigned short* __restrict__ Abuf,   // mean [N][128] bf16
        const unsigned short* __restrict__ Hbuf,   // root [N][128] bf16
        const unsigned short* __restrict__ Wcat,   // [128][256] bf16
        const float* __restrict__ bias,            // [128] fp32
        unsigned short* __restrict__ outb,
        unsigned char* __restrict__ out8,
        int N) {
    __shared__ unsigned short As[128 * 256];   // 64KB; reused as transpose buffer

    const int tid = threadIdx.x, wid = tid >> 6, lane = tid & 63;
    const int m0 = blockIdx.x * 128;
    char* Ac = (char*)As;
    const char* Ab = (const char*)Abuf;
    const char* Hb = (const char*)Hbuf;
    const char* Wb = (const char*)Wcat;

#pragma unroll
    for (int i = 0; i < 16; ++i) {
        int off = wid * 16384 + i * 1024 + lane * 16;
        int row = off >> 9, c = off & 511;
        int c2 = c ^ ((row & 7) << 4);
        const char* srcp = (c2 < 256) ? (Ab + (size_t)(m0 + row) * 256 + c2)
                                      : (Hb + (size_t)(m0 + row) * 256 + (c2 - 256));
        gld_lds16(srcp, Ac + wid * 16384 + i * 1024);
    }
    asm volatile("s_waitcnt vmcnt(0)" ::: "memory");
    __syncthreads();

    constexpr int MI = 4;
    constexpr int NI = 4;
    const int lm = lane & 15, ko = lane >> 4;
    const int wmBase = (wid >> 1) * 64;
    const int wnBase = (wid & 1) * 64;

    f32x4 acc[MI][NI];
#pragma unroll
    for (int i = 0; i < MI; ++i)
#pragma unroll
        for (int j = 0; j < NI; ++j)
            acc[i][j] = (f32x4){0.f, 0.f, 0.f, 0.f};

#pragma unroll
    for (int ks = 0; ks < 8; ++ks) {
        const int kb = ks * 64 + ko * 16;
        bf16x8 a[MI], b[NI];
#pragma unroll
        for (int j = 0; j < NI; ++j) {
            int row = wnBase + j * 16 + lm;
            b[j] = *(const bf16x8*)(Wb + row * 512 + kb);   // direct global (L2-hot)
        }
#pragma unroll
        for (int i = 0; i < MI; ++i) {
            int row = wmBase + i * 16 + lm;
            a[i] = *(const bf16x8*)(Ac + row * 512 + (kb ^ ((row & 7) << 4)));
        }
#pragma unroll
        for (int i = 0; i < MI; ++i)
#pragma unroll
            for (int j = 0; j < NI; ++j)
                acc[i][j] = __builtin_amdgcn_mfma_f32_16x16x32_bf16(b[j], a[i], acc[i][j], 0, 0, 0);
    }

    // ---- epilogue: bias+relu -> LDS transpose (272B-pad rows) -> coalesced ----
    __syncthreads();   // all As reads done
#pragma unroll
    for (int i = 0; i < MI; ++i) {
        const int r = wmBase + i * 16 + lm;
#pragma unroll
        for (int j = 0; j < NI; ++j) {
            const int col0 = wnBase + j * 16 + ko * 4;
            const float4 bv = *(const float4*)&bias[col0];
            float v0 = fmaxf(acc[i][j][0] + bv.x, 0.f);
            float v1 = fmaxf(acc[i][j][1] + bv.y, 0.f);
            float v2 = fmaxf(acc[i][j][2] + bv.z, 0.f);
            float v3 = fmaxf(acc[i][j][3] + bv.w, 0.f);
            uint2 o;
            o.x = (unsigned int)f2b(v0) | ((unsigned int)f2b(v1) << 16);
            o.y = (unsigned int)f2b(v2) | ((unsigned int)f2b(v3) << 16);
            *(uint2*)(Ac + r * 272 + col0 * 2) = o;
        }
    }
    __syncthreads();
    // 128 rows x 256B = 2048 chunks of 16B; 8 chunks/thread, lane-consecutive
#pragma unroll
    for (int p = 0; p < 8; ++p) {
        const int chunk = tid + p * 256;
        const int row = chunk >> 4;
        const int off = (chunk & 15) * 16;
        const int node = m0 + row;
        if (node >= N) continue;
        uint4 q = *(const uint4*)(Ac + row * 272 + off);
        *(uint4*)((char*)outb + (size_t)node * 256 + off) = q;
        if (OUT8) {
            float f0 = __uint_as_float(q.x << 16), f1 = __uint_as_float(q.x & 0xffff0000u);
            float f2 = __uint_as_float(q.y << 16), f3 = __uint_as_float(q.y & 0xffff0000u);
            float f4 = __uint_as_float(q.z << 16), f5 = __uint_as_float(q.z & 0xffff0000u);
            float f6 = __uint_as_float(q.w << 16), f7 = __uint_as_float(q.w & 0xffff0000u);
            unsigned p0 = __builtin_amdgcn_cvt_pk_fp8_f32(f0, f1, 0, false);
            p0 = __builtin_amdgcn_cvt_pk_fp8_f32(f2, f3, p0, true);
            unsigned p1 = __builtin_amdgcn_cvt_pk_fp8_f32(f4, f5, 0, false);
            p1 = __builtin_amdgcn_cvt_pk_fp8_f32(f6, f7, p1, true);
            uint2 o8 = make_uint2(p0, p1);
            *(uint2*)((char*)out8 + (size_t)node * 128 + (off >> 1)) = o8;
        }
    }
}

// ---------- MFMA GEMM (layer 2): z = h @ Wst^T + bst  (K=128, bf16 out) -------
// Same structure; LDS sized for the 272B-pad transpose (34.8KB -> 4 blocks/CU).

__global__ __launch_bounds__(256) void gemmz_kernel(
        const unsigned short* __restrict__ A,    // [N][128] bf16
        const unsigned short* __restrict__ W,    // [128][128] bf16
        const float* __restrict__ bias,          // [128] fp32
        unsigned short* __restrict__ outb,       // [N][128] bf16
        int N) {
    __shared__ unsigned short As[17408];   // max(32KB stage, 128x272B transpose)

    const int tid = threadIdx.x, wid = tid >> 6, lane = tid & 63;
    const int m0 = blockIdx.x * 128;
    char* Ac = (char*)As;
    const char* Ab = (const char*)A;
    const char* Wb = (const char*)W;

#pragma unroll
    for (int i = 0; i < 8; ++i) {
        int off = wid * 8192 + i * 1024 + lane * 16;
        int row = off >> 8, c = off & 255;
        int c2 = c ^ ((row & 7) << 4);
        gld_lds16(Ab + (size_t)(m0 + row) * 256 + c2, Ac + wid * 8192 + i * 1024);
    }
    asm volatile("s_waitcnt vmcnt(0)" ::: "memory");
    __syncthreads();

    const int lm = lane & 15, ko = lane >> 4;
    const int wmBase = (wid >> 1) * 64;
    const int wnBase = (wid & 1) * 64;

    f32x4 acc[4][4];
#pragma unroll
    for (int i = 0; i < 4; ++i)
#pragma unroll
        for (int j = 0; j < 4; ++j)
            acc[i][j] = (f32x4){0.f, 0.f, 0.f, 0.f};

#pragma unroll
    for (int ks = 0; ks < 4; ++ks) {
        const int kb = ks * 64 + ko * 16;
        bf16x8 a[4], b[4];
#pragma unroll
        for (int j = 0; j < 4; ++j) {
            int row = wnBase + j * 16 + lm;
            b[j] = *(const bf16x8*)(Wb + row * 256 + kb);   // direct global (L2-hot)
        }
#pragma unroll
        for (int i = 0; i < 4; ++i) {
            int row = wmBase + i * 16 + lm;
            a[i] = *(const bf16x8*)(Ac + row * 256 + (kb ^ ((row & 7) << 4)));
        }
#pragma unroll
        for (int i = 0; i < 4; ++i)
#pragma unroll
            for (int j = 0; j < 4; ++j)
                acc[i][j] = __builtin_amdgcn_mfma_f32_16x16x32_bf16(b[j], a[i], acc[i][j], 0, 0, 0);
    }

    // ---- transposed coalesced epilogue ----
    __syncthreads();
#pragma unroll
    for (int i = 0; i < 4; ++i) {
        const int r = wmBase + i * 16 + lm;
#pragma unroll
        for (int j = 0; j < 4; ++j) {
            const int col0 = wnBase + j * 16 + ko * 4;
            const float4 bv = *(const float4*)&bias[col0];
            uint2 o;
            o.x = (unsigned int)f2b(acc[i][j][0] + bv.x) |
                  ((unsigned int)f2b(acc[i][j][1] + bv.y) << 16);
            o.y = (unsigned int)f2b(acc[i][j][2] + bv.z) |
                  ((unsigned int)f2b(acc[i][j][3] + bv.w) << 16);
            *(uint2*)(Ac + r * 272 + col0 * 2) = o;
        }
    }
    __syncthreads();
#pragma unroll
    for (int p = 0; p < 8; ++p) {
        const int chunk = tid + p * 256;
        const int row = chunk >> 4;
        const int off = (chunk & 15) * 16;
        const int node = m0 + row;
        if (node >= N) continue;
        uint4 q = *(const uint4*)(Ac + row * 272 + off);
        *(uint4*)((char*)outb + (size_t)node * 256 + off) = q;
    }
}

// ---------------- launch ----------------

extern "C" void kernel_launch(void* const* d_in, const int* in_sizes, int n_in,
                              void* d_out, int out_size, void* d_ws, size_t ws_size,
                              hipStream_t stream) {
    const float* x   = (const float*)d_in[0];
    const int*   ei  = (const int*)d_in[1];
    const float* Wl0 = (const float*)d_in[2];
    const float* Wr0 = (const float*)d_in[3];
    const float* b0  = (const float*)d_in[4];
    const float* Wl1 = (const float*)d_in[5];
    const float* Wr1 = (const float*)d_in[6];
    const float* b1  = (const float*)d_in[7];
    const float* Wl2 = (const float*)d_in[8];
    const float* Wr2 = (const float*)d_in[9];
    const float* b2  = (const float*)d_in[10];
    float* out = (float*)d_out;

    const int N = in_sizes[0] / NF;
    const int E = in_sizes[1] / 2;
    const int* srcv = ei;
    const int* dstv = ei + E;

    const int NB   = (N + 255) >> 8;
    const int NBLK = (E + CHUNK - 1) / CHUNK;
    const int T    = NB * NBLK;
    const int NS   = (T + 255) / 256;

    char* w = (char*)d_ws;
    auto alloc = [&](size_t bytes) {
        void* p = (void*)w;
        w += (bytes + 255) & ~(size_t)255;
        return p;
    };
    unsigned short* xb   = (unsigned short*)alloc((size_t)N * NF * 2);
    unsigned short* h1b  = (unsigned short*)alloc((size_t)N * NF * 2);
    unsigned short* h2b  = (unsigned short*)alloc((size_t)N * NF * 2);
    unsigned short* mb   = (unsigned short*)alloc((size_t)N * NF * 2);
    // fp8 region (25.6 MB): x8 + h18 while live; z2b aliases it afterwards
    unsigned char*  u8   = (unsigned char*)alloc((size_t)N * NF * 2);
    unsigned char*  x8   = u8;                       // [N][128] fp8
    unsigned char*  h18  = u8 + (size_t)N * NF;      // [N][128] fp8
    unsigned short* z2b  = (unsigned short*)u8;      // [N][128] bf16 (after x8/h18 dead)
    unsigned short* Wc0  = (unsigned short*)alloc((size_t)128 * 256 * 2);
    unsigned short* Wc1  = (unsigned short*)alloc((size_t)128 * 256 * 2);
    unsigned short* Wst2 = (unsigned short*)alloc((size_t)128 * 128 * 2);
    float*          bst2 = (float*)alloc((size_t)128 * 4);
    int*   offs   = (int*)alloc((size_t)(N + 1) * 4);
    int*   csr    = (int*)alloc((size_t)E * 4);
    float* rdeg   = (float*)alloc((size_t)N * 4);
    unsigned int* recs = (unsigned int*)alloc((size_t)E * 4);
    int*   hist   = (int*)alloc((size_t)T * 4);
    int*   base   = (int*)alloc((size_t)T * 4);
    int*   bstart = (int*)alloc((size_t)(NB + 1) * 4);
    int*   sb1    = (int*)alloc((size_t)1024 * 4);
    int*   sb2    = (int*)alloc((size_t)1024 * 4);

    const int n4 = N * NF / 4;
    const int bCvt = (n4 + 255) / 256;
    const int bW0  = bCvt + 64;            // wcat0: 16384/256
    const int bW1  = bW0 + 64;             // wcat1
    const int bWs  = bW1 + 32;             // wstack: 8192/256
    const int bTot = bWs + NBLK;           // + hist

    prep_kernel<<<bTot, 256, 0, stream>>>(x, xb, x8, n4,
                                          Wl0, Wr0, Wc0, Wl1, Wr1, Wc1,
                                          Wl2, Wr2, b2, Wst2, bst2,
                                          dstv, hist, E, NB,
                                          bCvt, bW0, bW1, bWs);
    sb_sum<<<NS, 256, 0, stream>>>(hist, sb1, T, NB, NBLK);
    sb_scan<<<1, 1024, 0, stream>>>(sb1, sb2, NS);
    sb_apply<<<NS, 256, 0, stream>>>(hist, sb2, base, bstart, T, NB, NBLK, E);
    scat_kernel<<<NBLK, 256, 0, stream>>>(srcv, dstv, base, recs, E, NB, NBLK);
    csr_kernel<<<NB, 256, 0, stream>>>(recs, bstart, offs, rdeg, csr, N, E);

    const int ab  = (N + 3) / 4;
    const int gb  = (N + 127) / 128;

    // layer 0: mean from fp8 x; gemm also emits fp8 h1 for next gather
    agg8_kernel<<<ab, 256, 0, stream>>>(x8, offs, csr, rdeg, mb, N);
    gemm_kernel<true><<<gb, 256, 0, stream>>>(mb, xb, Wc0, b0, h1b, h18, N);

    // layer 1: mean from fp8 h1, root bf16 h1
    agg8_kernel<<<ab, 256, 0, stream>>>(h18, offs, csr, rdeg, mb, N);
    gemm_kernel<false><<<gb, 256, 0, stream>>>(mb, h1b, Wc1, b1, h2b, nullptr, N);

    // layer 2: transform-first (bf16), fused final agg
    gemmz_kernel<<<gb, 256, 0, stream>>>(h2b, Wst2, bst2, z2b, N);
    agg2_kernel<<<ab, 256, 0, stream>>>(z2b, offs, csr, rdeg, out, N);
}

// Round 16
// 258.784 us; speedup vs baseline: 1.3369x; 1.0778x over previous
//
#include <hip/hip_runtime.h>

#define NF 128      // feature width for x / hidden layers
#define CHUNK 8192  // edges per block in CSR-build phase 1

typedef __attribute__((ext_vector_type(8))) short bf16x8;
typedef __attribute__((ext_vector_type(4))) float f32x4;
typedef __attribute__((ext_vector_type(2))) float f32x2;

__device__ __forceinline__ unsigned short f2b(float f) {
    unsigned int u = __float_as_uint(f);
    unsigned int r = (u + 0x7fffu + ((u >> 16) & 1u)) >> 16;  // round-nearest-even
    return (unsigned short)r;
}

// async global->LDS, 16B per lane. LDS dest = wave-uniform base (+lane*16 by HW);
// global src is per-lane.
__device__ __forceinline__ void gld_lds16(const void* g, const void* l) {
    __builtin_amdgcn_global_load_lds(
        (const __attribute__((address_space(1))) unsigned int*)(unsigned long long)g,
        (__attribute__((address_space(3))) unsigned int*)(unsigned int)(unsigned long long)l,
        16, 0, 0);
}

// ========== fused prep: cvt(+fp8) | wcat0 | wcat1 | wstack | hist ============

__global__ __launch_bounds__(256) void prep_kernel(
        const float* __restrict__ x, unsigned short* __restrict__ xb,
        unsigned char* __restrict__ x8, int n4,
        const float* __restrict__ Wl0, const float* __restrict__ Wr0, unsigned short* __restrict__ Wc0,
        const float* __restrict__ Wl1, const float* __restrict__ Wr1, unsigned short* __restrict__ Wc1,
        const float* __restrict__ Wl2, const float* __restrict__ Wr2, const float* __restrict__ b2,
        unsigned short* __restrict__ Wst, float* __restrict__ bst,
        const int* __restrict__ dst, int* __restrict__ hist, int E, int NB,
        int bCvt, int bW0, int bW1, int bWs) {
    __shared__ int hsh[512];
    const int blk = blockIdx.x;
    const int tid = threadIdx.x;
    if (blk < bCvt) {
        int i = blk * 256 + tid;
        if (i < n4) {
            float4 v = *(const float4*)&x[(size_t)i * 4];
            uint2 o;
            o.x = (unsigned int)f2b(v.x) | ((unsigned int)f2b(v.y) << 16);
            o.y = (unsigned int)f2b(v.z) | ((unsigned int)f2b(v.w) << 16);
            *(uint2*)&xb[(size_t)i * 4] = o;
            unsigned p = __builtin_amdgcn_cvt_pk_fp8_f32(v.x, v.y, 0, false);
            p = __builtin_amdgcn_cvt_pk_fp8_f32(v.z, v.w, p, true);
            *(unsigned int*)&x8[(size_t)i * 4] = p;
        }
    } else if (blk < bW1) {
        const bool first = blk < bW0;
        int i = (blk - (first ? bCvt : bW0)) * 256 + tid;  // < 16384
        const float* Wl = first ? Wl0 : Wl1;
        const float* Wr = first ? Wr0 : Wr1;
        unsigned short* Wc = first ? Wc0 : Wc1;
        int f = i >> 7, k = i & 127;
        Wc[f * 256 + k] = f2b(Wl[i]);
        Wc[f * 256 + 128 + k] = f2b(Wr[i]);
    } else if (blk < bWs) {
        int i = (blk - bW1) * 256 + tid;  // < 8192
        int f = i >> 7, k = i & 127;
        Wst[f * 128 + k] = f2b(Wl2[i]);
        Wst[(f + 64) * 128 + k] = f2b(Wr2[i]);
        if (k == 0) {
            bst[f] = 0.f;
            bst[f + 64] = b2[f];
        }
    } else {
        const int hb = blk - bWs;  // hist block
        for (int i = tid; i < NB; i += 256) hsh[i] = 0;
        __syncthreads();
        const int e0 = hb * CHUNK;
        for (int i = tid; i < CHUNK; i += 256) {
            int e = e0 + i;
            if (e < E) atomicAdd(&hsh[dst[e] >> 8], 1);
        }
        __syncthreads();
        for (int i = tid; i < NB; i += 256) hist[hb * NB + i] = hsh[i];
    }
}

// ================= CSR build scan chain =================

__global__ __launch_bounds__(256) void sb_sum(const int* __restrict__ hist,
                                              int* __restrict__ bsum,
                                              int T, int NB, int NBLK) {
    int i = blockIdx.x * 256 + threadIdx.x;
    int v = 0;
    if (i < T) {
        int b = i / NBLK, blk = i - b * NBLK;
        v = hist[blk * NB + b];
    }
#pragma unroll
    for (int d = 32; d; d >>= 1) v += __shfl_down(v, d, 64);
    __shared__ int wsum[4];
    if ((threadIdx.x & 63) == 0) wsum[threadIdx.x >> 6] = v;
    __syncthreads();
    if (threadIdx.x == 0) bsum[blockIdx.x] = wsum[0] + wsum[1] + wsum[2] + wsum[3];
}

__global__ __launch_bounds__(1024) void sb_scan(const int* __restrict__ bsum,
                                                int* __restrict__ bpre, int NS) {
    __shared__ int s[1024];
    int t = threadIdx.x;
    int v = (t < NS) ? bsum[t] : 0;
    s[t] = v;
    __syncthreads();
    for (int d = 1; d < 1024; d <<= 1) {
        int u = (t >= d) ? s[t - d] : 0;
        __syncthreads();
        s[t] += u;
        __syncthreads();
    }
    if (t < NS) bpre[t] = s[t] - v;
}

__global__ __launch_bounds__(256) void sb_apply(const int* __restrict__ hist,
                                                const int* __restrict__ bpre,
                                                int* __restrict__ base,
                                                int* __restrict__ bstart,
                                                int T, int NB, int NBLK, int E) {
    __shared__ int s[256];
    int i = blockIdx.x * 256 + threadIdx.x;
    int t = threadIdx.x;
    int v = 0;
    int b = 0, blk = 0;
    if (i < T) {
        b = i / NBLK;
        blk = i - b * NBLK;
        v = hist[blk * NB + b];
    }
    s[t] = v;
    __syncthreads();
    for (int d = 1; d < 256; d <<= 1) {
        int u = (t >= d) ? s[t - d] : 0;
        __syncthreads();
        s[t] += u;
        __syncthreads();
    }
    if (i < T) {
        int val = bpre[blockIdx.x] + s[t] - v;
        base[i] = val;
        if (blk == 0) bstart[b] = val;
        if (i == 0) bstart[NB] = E;
    }
}

__global__ __launch_bounds__(256) void scat_kernel(const int* __restrict__ src,
                                                   const int* __restrict__ dst,
                                                   const int* __restrict__ base,
                                                   unsigned int* __restrict__ recs,
                                                   int E, int NB, int NBLK) {
    __shared__ int cur[512];
    const int blk = blockIdx.x;
    for (int b = threadIdx.x; b < NB; b += 256) cur[b] = base[b * NBLK + blk];
    __syncthreads();
    const int e0 = blk * CHUNK;
    for (int i = threadIdx.x; i < CHUNK; i += 256) {
        int e = e0 + i;
        if (e >= E) continue;
        int d = dst[e];
        int b = d >> 8;
        int pos = atomicAdd(&cur[b], 1);
        recs[pos] = (unsigned int)src[e] | ((unsigned int)(d & 255) << 24);
    }
}

__global__ __launch_bounds__(256) void csr_kernel(const unsigned int* __restrict__ recs,
                                                  const int* __restrict__ bstart,
                                                  int* __restrict__ offs,
                                                  float* __restrict__ rdeg,
                                                  int* __restrict__ csr,
                                                  int N, int E) {
    __shared__ int cnt[256];
    __shared__ int sc[256];
    __shared__ int cur[256];
    const int b = blockIdx.x;
    const int t = threadIdx.x;
    const int s0 = bstart[b], s1 = bstart[b + 1];
    cnt[t] = 0;
    __syncthreads();
    for (int i = s0 + t; i < s1; i += 256) atomicAdd(&cnt[recs[i] >> 24], 1);
    __syncthreads();
    int v = cnt[t];
    sc[t] = v;
    __syncthreads();
    for (int d = 1; d < 256; d <<= 1) {
        int u = (t >= d) ? sc[t - d] : 0;
        __syncthreads();
        sc[t] += u;
        __syncthreads();
    }
    int excl = sc[t] - v;
    int node = b * 256 + t;
    if (node < N) {
        offs[node] = s0 + excl;
        rdeg[node] = 1.0f / (float)(v > 1 ? v : 1);
        if (node == N - 1) offs[N] = E;
    }
    cur[t] = s0 + excl;
    __syncthreads();
    for (int i = s0 + t; i < s1; i += 256) {
        unsigned int r = recs[i];
        int pos = atomicAdd(&cur[r >> 24], 1);
        csr[pos] = (int)(r & 0xFFFFFFu);
    }
}

// -------- mean aggregation from FP8 rows (128B/row), bf16 mean out -----------

__global__ __launch_bounds__(256) void agg8_kernel(
        const unsigned char* __restrict__ h8, const int* __restrict__ offs,
        const int* __restrict__ csr, const float* __restrict__ rdeg,
        unsigned short* __restrict__ meanout, int N) {
    const int node = blockIdx.x * 4 + (threadIdx.x >> 6);
    const int lane = threadIdx.x & 63;
    if (node >= N) return;
    const int s0 = offs[node], s1 = offs[node + 1];
    const char* __restrict__ hb = (const char*)h8;
    const unsigned lane2 = (unsigned)lane * 2u;
    f32x2 acc = {0.f, 0.f};
    for (int base = s0; base < s1; base += 64) {
        const int cnt = min(64, s1 - base);
        const int boff = csr[base + min(lane, cnt - 1)] << 7;  // fp8 row byte offset
        int j = 0;
#define AGG8_GROUP(NG)                                                         \
        {                                                                      \
            unsigned o[NG];                                                    \
            _Pragma("unroll")                                                  \
            for (int k = 0; k < NG; ++k)                                       \
                o[k] = (unsigned)__shfl(boff, j + k, 64) + lane2;              \
            unsigned int v[NG];                                                \
            _Pragma("unroll")                                                  \
            for (int k = 0; k < NG; ++k)                                       \
                v[k] = *(const unsigned short*)(hb + o[k]);                    \
            _Pragma("unroll")                                                  \
            for (int k = 0; k < NG; ++k)                                       \
                acc += __builtin_amdgcn_cvt_pk_f32_fp8(v[k], false);           \
            j += NG;                                                           \
        }
        while (j + 16 <= cnt) AGG8_GROUP(16)
        if (cnt & 8) AGG8_GROUP(8)
        if (cnt & 4) AGG8_GROUP(4)
        if (cnt & 2) AGG8_GROUP(2)
        if (cnt & 1) AGG8_GROUP(1)
#undef AGG8_GROUP
    }
    float r = rdeg[node];
    unsigned int o = (unsigned int)f2b(acc.x * r) | ((unsigned int)f2b(acc.y * r) << 16);
    *(unsigned int*)&meanout[(size_t)node * NF + lane * 2] = o;
}

// ---- layer-2 final agg: out[i] = mean_j zl[j] + zr[i]  (fp32 out) -----------

__global__ __launch_bounds__(256) void agg2_kernel(
        const unsigned short* __restrict__ z, const int* __restrict__ offs,
        const int* __restrict__ csr, const float* __restrict__ rdeg,
        float* __restrict__ out, int N) {
    const int node = blockIdx.x * 4 + (threadIdx.x >> 6);
    const int lane = threadIdx.x & 63;
    if (node >= N) return;
    const int s0 = offs[node], s1 = offs[node + 1];
    const char* __restrict__ zb = (const char*)z;
    const unsigned lane2 = (unsigned)lane * 2u;
    float acc = 0.f;
    for (int base = s0; base < s1; base += 64) {
        const int cnt = min(64, s1 - base);
        const int boff = csr[base + min(lane, cnt - 1)] << 8;  // zl = first 128B of 256B row
        int j = 0;
#define AGG2_GROUP(NG)                                                         \
        {                                                                      \
            unsigned o[NG];                                                    \
            _Pragma("unroll")                                                  \
            for (int k = 0; k < NG; ++k)                                       \
                o[k] = (unsigned)__shfl(boff, j + k, 64) + lane2;              \
            unsigned int v[NG];                                                \
            _Pragma("unroll")                                                  \
            for (int k = 0; k < NG; ++k)                                       \
                v[k] = *(const unsigned short*)(zb + o[k]);                    \
            _Pragma("unroll")                                                  \
            for (int k = 0; k < NG; ++k)                                       \
                acc += __uint_as_float(v[k] << 16);                            \
            j += NG;                                                           \
        }
        while (j + 16 <= cnt) AGG2_GROUP(16)
        if (cnt & 8) AGG2_GROUP(8)
        if (cnt & 4) AGG2_GROUP(4)
        if (cnt & 2) AGG2_GROUP(2)
        if (cnt & 1) AGG2_GROUP(1)
#undef AGG2_GROUP
    }
    float r = rdeg[node];
    unsigned int vr = *(const unsigned short*)(zb + (size_t)node * 256 + 128 + lane2);
    out[(size_t)node * 64 + lane] = acc * r + __uint_as_float(vr << 16);
}

// ------- MFMA GEMM (layers 0/1): out = [mean|h] @ Wcat^T + b, relu, bf16 out ---
// BM=64 x BN=64; BOTH A and W staged in LDS (coalesced gld_lds16) -> the k-loop
// issues ZERO global requests (request-rate cap is the chip bottleneck).
// Coalesced transposed epilogue. blockIdx = (mtile<<1)|colHalf.

template <bool OUT8>
__global__ __launch_bounds__(256, 2) void gemm_kernel(
        const unsigned short* __restrict__ Abuf,   // mean [N][128] bf16
        const unsigned short* __restrict__ Hbuf,   // root [N][128] bf16
        const unsigned short* __restrict__ Wcat,   // [128][256] bf16
        const float* __restrict__ bias,            // [128] fp32
        unsigned short* __restrict__ outb,
        unsigned char* __restrict__ out8,
        int N) {
    __shared__ char LDS[65536];   // A 32KB | W 32KB; A region reused for transpose

    const int tid = threadIdx.x, wid = tid >> 6, lane = tid & 63;
    const int half = blockIdx.x & 1;
    const int m0 = (blockIdx.x >> 1) * 64;
    const int c0 = half * 64;
    char* Ac = LDS;
    char* Wc = LDS + 32768;
    const char* Ab = (const char*)Abuf;
    const char* Hb = (const char*)Hbuf;
    const char* Wb = (const char*)Wcat;

    // stage A: 64 rows x 512B ([mean|root]), pre-swizzled source
#pragma unroll
    for (int i = 0; i < 8; ++i) {
        int off = wid * 8192 + i * 1024 + lane * 16;
        int row = off >> 9, c = off & 511;
        int c2 = c ^ ((row & 7) << 4);
        int g = min(m0 + row, N - 1);
        const char* srcp = (c2 < 256) ? (Ab + (size_t)g * 256 + c2)
                                      : (Hb + (size_t)g * 256 + (c2 - 256));
        gld_lds16(srcp, Ac + wid * 8192 + i * 1024);
    }
    // stage W: rows c0..c0+63 x 512B, same swizzle
#pragma unroll
    for (int i = 0; i < 8; ++i) {
        int off = wid * 8192 + i * 1024 + lane * 16;
        int row = off >> 9, c = off & 511;
        int c2 = c ^ ((row & 7) << 4);
        gld_lds16(Wb + (size_t)(c0 + row) * 512 + c2, Wc + wid * 8192 + i * 1024);
    }
    asm volatile("s_waitcnt vmcnt(0)" ::: "memory");
    __syncthreads();

    const int lm = lane & 15, ko = lane >> 4;
    const int wm = wid >> 1, wn = wid & 1;   // 2x2 waves, each 32x32 out

    f32x4 acc[2][2];
#pragma unroll
    for (int i = 0; i < 2; ++i)
#pragma unroll
        for (int j = 0; j < 2; ++j)
            acc[i][j] = (f32x4){0.f, 0.f, 0.f, 0.f};

#pragma unroll
    for (int ks = 0; ks < 8; ++ks) {
        const int kb = ks * 64 + ko * 16;
        bf16x8 a[2], b[2];
#pragma unroll
        for (int j = 0; j < 2; ++j) {
            int row = wn * 32 + j * 16 + lm;
            b[j] = *(const bf16x8*)(Wc + row * 512 + (kb ^ ((row & 7) << 4)));
        }
#pragma unroll
        for (int i = 0; i < 2; ++i) {
            int row = wm * 32 + i * 16 + lm;
            a[i] = *(const bf16x8*)(Ac + row * 512 + (kb ^ ((row & 7) << 4)));
        }
#pragma unroll
        for (int i = 0; i < 2; ++i)
#pragma unroll
            for (int j = 0; j < 2; ++j)
                acc[i][j] = __builtin_amdgcn_mfma_f32_16x16x32_bf16(b[j], a[i], acc[i][j], 0, 0, 0);
    }

    // ---- epilogue: bias+relu -> LDS transpose (144B-pad rows) -> coalesced ----
    __syncthreads();
#pragma unroll
    for (int i = 0; i < 2; ++i) {
        const int r = wm * 32 + i * 16 + lm;
#pragma unroll
        for (int j = 0; j < 2; ++j) {
            const int lcol = wn * 32 + j * 16 + ko * 4;
            const float4 bv = *(const float4*)&bias[c0 + lcol];
            float v0 = fmaxf(acc[i][j][0] + bv.x, 0.f);
            float v1 = fmaxf(acc[i][j][1] + bv.y, 0.f);
            float v2 = fmaxf(acc[i][j][2] + bv.z, 0.f);
            float v3 = fmaxf(acc[i][j][3] + bv.w, 0.f);
            uint2 o;
            o.x = (unsigned int)f2b(v0) | ((unsigned int)f2b(v1) << 16);
            o.y = (unsigned int)f2b(v2) | ((unsigned int)f2b(v3) << 16);
            *(uint2*)(Ac + r * 144 + lcol * 2) = o;
        }
    }
    __syncthreads();
    // 64 rows x 128B = 512 chunks of 16B; 2 chunks/thread
#pragma unroll
    for (int p = 0; p < 2; ++p) {
        const int chunk = tid + p * 256;
        const int row = chunk >> 3;
        const int off = (chunk & 7) * 16;
        const int node = m0 + row;
        if (node >= N) continue;
        uint4 q = *(const uint4*)(Ac + row * 144 + off);
        *(uint4*)((char*)outb + (size_t)node * 256 + c0 * 2 + off) = q;
        if (OUT8) {
            float f0 = __uint_as_float(q.x << 16), f1 = __uint_as_float(q.x & 0xffff0000u);
            float f2 = __uint_as_float(q.y << 16), f3 = __uint_as_float(q.y & 0xffff0000u);
            float f4 = __uint_as_float(q.z << 16), f5 = __uint_as_float(q.z & 0xffff0000u);
            float f6 = __uint_as_float(q.w << 16), f7 = __uint_as_float(q.w & 0xffff0000u);
            unsigned p0 = __builtin_amdgcn_cvt_pk_fp8_f32(f0, f1, 0, false);
            p0 = __builtin_amdgcn_cvt_pk_fp8_f32(f2, f3, p0, true);
            unsigned p1 = __builtin_amdgcn_cvt_pk_fp8_f32(f4, f5, 0, false);
            p1 = __builtin_amdgcn_cvt_pk_fp8_f32(f6, f7, p1, true);
            uint2 o8 = make_uint2(p0, p1);
            *(uint2*)((char*)out8 + (size_t)node * 128 + c0 + (off >> 1)) = o8;
        }
    }
}

// ---------- MFMA GEMM (layer 2): z = h @ Wst^T + bst  (K=128, bf16 out) -------
// Same both-staged structure; A 16KB + W 16KB = 32KB -> 5 blocks/CU.

__global__ __launch_bounds__(256, 2) void gemmz_kernel(
        const unsigned short* __restrict__ A,    // [N][128] bf16
        const unsigned short* __restrict__ W,    // [128][128] bf16
        const float* __restrict__ bias,          // [128] fp32
        unsigned short* __restrict__ outb,       // [N][128] bf16
        int N) {
    __shared__ char LDS[32768];   // A 16KB | W 16KB; A reused for transpose (9.2KB)

    const int tid = threadIdx.x, wid = tid >> 6, lane = tid & 63;
    const int half = blockIdx.x & 1;
    const int m0 = (blockIdx.x >> 1) * 64;
    const int c0 = half * 64;
    char* Ac = LDS;
    char* Wc = LDS + 16384;
    const char* Ab = (const char*)A;
    const char* Wb = (const char*)W;

#pragma unroll
    for (int i = 0; i < 4; ++i) {
        int off = wid * 4096 + i * 1024 + lane * 16;
        int row = off >> 8, c = off & 255;
        int c2 = c ^ ((row & 7) << 4);
        int g = min(m0 + row, N - 1);
        gld_lds16(Ab + (size_t)g * 256 + c2, Ac + wid * 4096 + i * 1024);
    }
#pragma unroll
    for (int i = 0; i < 4; ++i) {
        int off = wid * 4096 + i * 1024 + lane * 16;
        int row = off >> 8, c = off & 255;
        int c2 = c ^ ((row & 7) << 4);
        gld_lds16(Wb + (size_t)(c0 + row) * 256 + c2, Wc + wid * 4096 + i * 1024);
    }
    asm volatile("s_waitcnt vmcnt(0)" ::: "memory");
    __syncthreads();

    const int lm = lane & 15, ko = lane >> 4;
    const int wm = wid >> 1, wn = wid & 1;

    f32x4 acc[2][2];
#pragma unroll
    for (int i = 0; i < 2; ++i)
#pragma unroll
        for (int j = 0; j < 2; ++j)
            acc[i][j] = (f32x4){0.f, 0.f, 0.f, 0.f};

#pragma unroll
    for (int ks = 0; ks < 4; ++ks) {
        const int kb = ks * 64 + ko * 16;
        bf16x8 a[2], b[2];
#pragma unroll
        for (int j = 0; j < 2; ++j) {
            int row = wn * 32 + j * 16 + lm;
            b[j] = *(const bf16x8*)(Wc + row * 256 + (kb ^ ((row & 7) << 4)));
        }
#pragma unroll
        for (int i = 0; i < 2; ++i) {
            int row = wm * 32 + i * 16 + lm;
            a[i] = *(const bf16x8*)(Ac + row * 256 + (kb ^ ((row & 7) << 4)));
        }
#pragma unroll
        for (int i = 0; i < 2; ++i)
#pragma unroll
            for (int j = 0; j < 2; ++j)
                acc[i][j] = __builtin_amdgcn_mfma_f32_16x16x32_bf16(b[j], a[i], acc[i][j], 0, 0, 0);
    }

    __syncthreads();
#pragma unroll
    for (int i = 0; i < 2; ++i) {
        const int r = wm * 32 + i * 16 + lm;
#pragma unroll
        for (int j = 0; j < 2; ++j) {
            const int lcol = wn * 32 + j * 16 + ko * 4;
            const float4 bv = *(const float4*)&bias[c0 + lcol];
            uint2 o;
            o.x = (unsigned int)f2b(acc[i][j][0] + bv.x) |
                  ((unsigned int)f2b(acc[i][j][1] + bv.y) << 16);
            o.y = (unsigned int)f2b(acc[i][j][2] + bv.z) |
                  ((unsigned int)f2b(acc[i][j][3] + bv.w) << 16);
            *(uint2*)(Ac + r * 144 + lcol * 2) = o;
        }
    }
    __syncthreads();
#pragma unroll
    for (int p = 0; p < 2; ++p) {
        const int chunk = tid + p * 256;
        const int row = chunk >> 3;
        const int off = (chunk & 7) * 16;
        const int node = m0 + row;
        if (node >= N) continue;
        uint4 q = *(const uint4*)(Ac + row * 144 + off);
        *(uint4*)((char*)outb + (size_t)node * 256 + c0 * 2 + off) = q;
    }
}

// ---------------- launch ----------------

extern "C" void kernel_launch(void* const* d_in, const int* in_sizes, int n_in,
                              void* d_out, int out_size, void* d_ws, size_t ws_size,
                              hipStream_t stream) {
    const float* x   = (const float*)d_in[0];
    const int*   ei  = (const int*)d_in[1];
    const float* Wl0 = (const float*)d_in[2];
    const float* Wr0 = (const float*)d_in[3];
    const float* b0  = (const float*)d_in[4];
    const float* Wl1 = (const float*)d_in[5];
    const float* Wr1 = (const float*)d_in[6];
    const float* b1  = (const float*)d_in[7];
    const float* Wl2 = (const float*)d_in[8];
    const float* Wr2 = (const float*)d_in[9];
    const float* b2  = (const float*)d_in[10];
    float* out = (float*)d_out;

    const int N = in_sizes[0] / NF;
    const int E = in_sizes[1] / 2;
    const int* srcv = ei;
    const int* dstv = ei + E;

    const int NB   = (N + 255) >> 8;
    const int NBLK = (E + CHUNK - 1) / CHUNK;
    const int T    = NB * NBLK;
    const int NS   = (T + 255) / 256;

    char* w = (char*)d_ws;
    auto alloc = [&](size_t bytes) {
        void* p = (void*)w;
        w += (bytes + 255) & ~(size_t)255;
        return p;
    };
    unsigned short* xb   = (unsigned short*)alloc((size_t)N * NF * 2);
    unsigned short* h1b  = (unsigned short*)alloc((size_t)N * NF * 2);
    unsigned short* h2b  = (unsigned short*)alloc((size_t)N * NF * 2);
    unsigned short* mb   = (unsigned short*)alloc((size_t)N * NF * 2);
    // fp8 region (25.6 MB): x8 + h18 while live; z2b aliases it afterwards
    unsigned char*  u8   = (unsigned char*)alloc((size_t)N * NF * 2);
    unsigned char*  x8   = u8;                       // [N][128] fp8
    unsigned char*  h18  = u8 + (size_t)N * NF;      // [N][128] fp8
    unsigned short* z2b  = (unsigned short*)u8;      // [N][128] bf16 (after x8/h18 dead)
    unsigned short* Wc0  = (unsigned short*)alloc((size_t)128 * 256 * 2);
    unsigned short* Wc1  = (unsigned short*)alloc((size_t)128 * 256 * 2);
    unsigned short* Wst2 = (unsigned short*)alloc((size_t)128 * 128 * 2);
    float*          bst2 = (float*)alloc((size_t)128 * 4);
    int*   offs   = (int*)alloc((size_t)(N + 1) * 4);
    int*   csr    = (int*)alloc((size_t)E * 4);
    float* rdeg   = (float*)alloc((size_t)N * 4);
    unsigned int* recs = (unsigned int*)alloc((size_t)E * 4);
    int*   hist   = (int*)alloc((size_t)T * 4);
    int*   base   = (int*)alloc((size_t)T * 4);
    int*   bstart = (int*)alloc((size_t)(NB + 1) * 4);
    int*   sb1    = (int*)alloc((size_t)1024 * 4);
    int*   sb2    = (int*)alloc((size_t)1024 * 4);

    const int n4 = N * NF / 4;
    const int bCvt = (n4 + 255) / 256;
    const int bW0  = bCvt + 64;            // wcat0: 16384/256
    const int bW1  = bW0 + 64;             // wcat1
    const int bWs  = bW1 + 32;             // wstack: 8192/256
    const int bTot = bWs + NBLK;           // + hist

    prep_kernel<<<bTot, 256, 0, stream>>>(x, xb, x8, n4,
                                          Wl0, Wr0, Wc0, Wl1, Wr1, Wc1,
                                          Wl2, Wr2, b2, Wst2, bst2,
                                          dstv, hist, E, NB,
                                          bCvt, bW0, bW1, bWs);
    sb_sum<<<NS, 256, 0, stream>>>(hist, sb1, T, NB, NBLK);
    sb_scan<<<1, 1024, 0, stream>>>(sb1, sb2, NS);
    sb_apply<<<NS, 256, 0, stream>>>(hist, sb2, base, bstart, T, NB, NBLK, E);
    scat_kernel<<<NBLK, 256, 0, stream>>>(srcv, dstv, base, recs, E, NB, NBLK);
    csr_kernel<<<NB, 256, 0, stream>>>(recs, bstart, offs, rdeg, csr, N, E);

    const int ab  = (N + 3) / 4;
    const int gb2 = 2 * ((N + 63) / 64);   // (mtile, colHalf) grid

    // layer 0: mean from fp8 x; gemm also emits fp8 h1 for next gather
    agg8_kernel<<<ab, 256, 0, stream>>>(x8, offs, csr, rdeg, mb, N);
    gemm_kernel<true><<<gb2, 256, 0, stream>>>(mb, xb, Wc0, b0, h1b, h18, N);

    // layer 1: mean from fp8 h1, root bf16 h1
    agg8_kernel<<<ab, 256, 0, stream>>>(h18, offs, csr, rdeg, mb, N);
    gemm_kernel<false><<<gb2, 256, 0, stream>>>(mb, h1b, Wc1, b1, h2b, nullptr, N);

    // layer 2: transform-first (bf16), fused final agg
    gemmz_kernel<<<gb2, 256, 0, stream>>>(h2b, Wst2, bst2, z2b, N);
    agg2_kernel<<<ab, 256, 0, stream>>>(z2b, offs, csr, rdeg, out, N);
}

// Round 17
// 250.963 us; speedup vs baseline: 1.3786x; 1.0312x over previous
//
#include <hip/hip_runtime.h>

#define NF 128      // feature width for x / hidden layers
#define CHUNK 8192  // edges per block in CSR-build phase 1

typedef __attribute__((ext_vector_type(8))) short bf16x8;
typedef __attribute__((ext_vector_type(4))) float f32x4;
typedef __attribute__((ext_vector_type(2))) float f32x2;

__device__ __forceinline__ unsigned short f2b(float f) {
    unsigned int u = __float_as_uint(f);
    unsigned int r = (u + 0x7fffu + ((u >> 16) & 1u)) >> 16;  // round-nearest-even
    return (unsigned short)r;
}

// async global->LDS, 16B per lane. LDS dest = wave-uniform base (+lane*16 by HW);
// global src is per-lane.
__device__ __forceinline__ void gld_lds16(const void* g, const void* l) {
    __builtin_amdgcn_global_load_lds(
        (const __attribute__((address_space(1))) unsigned int*)(unsigned long long)g,
        (__attribute__((address_space(3))) unsigned int*)(unsigned int)(unsigned long long)l,
        16, 0, 0);
}

// ========== fused prep: cvt(+fp8) | wcat0 | wcat1 | wstack | hist ============

__global__ __launch_bounds__(256) void prep_kernel(
        const float* __restrict__ x, unsigned short* __restrict__ xb,
        unsigned char* __restrict__ x8, int n4,
        const float* __restrict__ Wl0, const float* __restrict__ Wr0, unsigned short* __restrict__ Wc0,
        const float* __restrict__ Wl1, const float* __restrict__ Wr1, unsigned short* __restrict__ Wc1,
        const float* __restrict__ Wl2, const float* __restrict__ Wr2, const float* __restrict__ b2,
        unsigned short* __restrict__ Wst, float* __restrict__ bst,
        const int* __restrict__ dst, int* __restrict__ hist, int E, int NB,
        int bCvt, int bW0, int bW1, int bWs) {
    __shared__ int hsh[512];
    const int blk = blockIdx.x;
    const int tid = threadIdx.x;
    if (blk < bCvt) {
        int i = blk * 256 + tid;
        if (i < n4) {
            float4 v = *(const float4*)&x[(size_t)i * 4];
            uint2 o;
            o.x = (unsigned int)f2b(v.x) | ((unsigned int)f2b(v.y) << 16);
            o.y = (unsigned int)f2b(v.z) | ((unsigned int)f2b(v.w) << 16);
            *(uint2*)&xb[(size_t)i * 4] = o;
            unsigned p = __builtin_amdgcn_cvt_pk_fp8_f32(v.x, v.y, 0, false);
            p = __builtin_amdgcn_cvt_pk_fp8_f32(v.z, v.w, p, true);
            *(unsigned int*)&x8[(size_t)i * 4] = p;
        }
    } else if (blk < bW1) {
        const bool first = blk < bW0;
        int i = (blk - (first ? bCvt : bW0)) * 256 + tid;  // < 16384
        const float* Wl = first ? Wl0 : Wl1;
        const float* Wr = first ? Wr0 : Wr1;
        unsigned short* Wc = first ? Wc0 : Wc1;
        int f = i >> 7, k = i & 127;
        Wc[f * 256 + k] = f2b(Wl[i]);
        Wc[f * 256 + 128 + k] = f2b(Wr[i]);
    } else if (blk < bWs) {
        int i = (blk - bW1) * 256 + tid;  // < 8192
        int f = i >> 7, k = i & 127;
        Wst[f * 128 + k] = f2b(Wl2[i]);
        Wst[(f + 64) * 128 + k] = f2b(Wr2[i]);
        if (k == 0) {
            bst[f] = 0.f;
            bst[f + 64] = b2[f];
        }
    } else {
        const int hb = blk - bWs;  // hist block
        for (int i = tid; i < NB; i += 256) hsh[i] = 0;
        __syncthreads();
        const int e0 = hb * CHUNK;
        for (int i = tid; i < CHUNK; i += 256) {
            int e = e0 + i;
            if (e < E) atomicAdd(&hsh[dst[e] >> 8], 1);
        }
        __syncthreads();
        for (int i = tid; i < NB; i += 256) hist[hb * NB + i] = hsh[i];
    }
}

// ================= CSR build scan chain =================

__global__ __launch_bounds__(256) void sb_sum(const int* __restrict__ hist,
                                              int* __restrict__ bsum,
                                              int T, int NB, int NBLK) {
    int i = blockIdx.x * 256 + threadIdx.x;
    int v = 0;
    if (i < T) {
        int b = i / NBLK, blk = i - b * NBLK;
        v = hist[blk * NB + b];
    }
#pragma unroll
    for (int d = 32; d; d >>= 1) v += __shfl_down(v, d, 64);
    __shared__ int wsum[4];
    if ((threadIdx.x & 63) == 0) wsum[threadIdx.x >> 6] = v;
    __syncthreads();
    if (threadIdx.x == 0) bsum[blockIdx.x] = wsum[0] + wsum[1] + wsum[2] + wsum[3];
}

__global__ __launch_bounds__(1024) void sb_scan(const int* __restrict__ bsum,
                                                int* __restrict__ bpre, int NS) {
    __shared__ int s[1024];
    int t = threadIdx.x;
    int v = (t < NS) ? bsum[t] : 0;
    s[t] = v;
    __syncthreads();
    for (int d = 1; d < 1024; d <<= 1) {
        int u = (t >= d) ? s[t - d] : 0;
        __syncthreads();
        s[t] += u;
        __syncthreads();
    }
    if (t < NS) bpre[t] = s[t] - v;
}

__global__ __launch_bounds__(256) void sb_apply(const int* __restrict__ hist,
                                                const int* __restrict__ bpre,
                                                int* __restrict__ base,
                                                int* __restrict__ bstart,
                                                int T, int NB, int NBLK, int E) {
    __shared__ int s[256];
    int i = blockIdx.x * 256 + threadIdx.x;
    int t = threadIdx.x;
    int v = 0;
    int b = 0, blk = 0;
    if (i < T) {
        b = i / NBLK;
        blk = i - b * NBLK;
        v = hist[blk * NB + b];
    }
    s[t] = v;
    __syncthreads();
    for (int d = 1; d < 256; d <<= 1) {
        int u = (t >= d) ? s[t - d] : 0;
        __syncthreads();
        s[t] += u;
        __syncthreads();
    }
    if (i < T) {
        int val = bpre[blockIdx.x] + s[t] - v;
        base[i] = val;
        if (blk == 0) bstart[b] = val;
        if (i == 0) bstart[NB] = E;
    }
}

__global__ __launch_bounds__(256) void scat_kernel(const int* __restrict__ src,
                                                   const int* __restrict__ dst,
                                                   const int* __restrict__ base,
                                                   unsigned int* __restrict__ recs,
                                                   int E, int NB, int NBLK) {
    __shared__ int cur[512];
    const int blk = blockIdx.x;
    for (int b = threadIdx.x; b < NB; b += 256) cur[b] = base[b * NBLK + blk];
    __syncthreads();
    const int e0 = blk * CHUNK;
    for (int i = threadIdx.x; i < CHUNK; i += 256) {
        int e = e0 + i;
        if (e >= E) continue;
        int d = dst[e];
        int b = d >> 8;
        int pos = atomicAdd(&cur[b], 1);
        recs[pos] = (unsigned int)src[e] | ((unsigned int)(d & 255) << 24);
    }
}

__global__ __launch_bounds__(256) void csr_kernel(const unsigned int* __restrict__ recs,
                                                  const int* __restrict__ bstart,
                                                  int* __restrict__ offs,
                                                  float* __restrict__ rdeg,
                                                  int* __restrict__ csr,
                                                  int N, int E) {
    __shared__ int cnt[256];
    __shared__ int sc[256];
    __shared__ int cur[256];
    const int b = blockIdx.x;
    const int t = threadIdx.x;
    const int s0 = bstart[b], s1 = bstart[b + 1];
    cnt[t] = 0;
    __syncthreads();
    for (int i = s0 + t; i < s1; i += 256) atomicAdd(&cnt[recs[i] >> 24], 1);
    __syncthreads();
    int v = cnt[t];
    sc[t] = v;
    __syncthreads();
    for (int d = 1; d < 256; d <<= 1) {
        int u = (t >= d) ? sc[t - d] : 0;
        __syncthreads();
        sc[t] += u;
        __syncthreads();
    }
    int excl = sc[t] - v;
    int node = b * 256 + t;
    if (node < N) {
        offs[node] = s0 + excl;
        rdeg[node] = 1.0f / (float)(v > 1 ? v : 1);
        if (node == N - 1) offs[N] = E;
    }
    cur[t] = s0 + excl;
    __syncthreads();
    for (int i = s0 + t; i < s1; i += 256) {
        unsigned int r = recs[i];
        int pos = atomicAdd(&cur[r >> 24], 1);
        csr[pos] = (int)(r & 0xFFFFFFu);
    }
}

// -------- mean aggregation from FP8 rows (128B/row), bf16 mean out -----------
// One node/wave. Fast path (cnt<=31, ~99.95%): issue ALL group loads back-to-
// back (one latency round-trip), then accumulate in the same 16/8/4/2/1 order
// (bitwise-identical). Rare cnt>=32 keeps the sequential path.

__global__ __launch_bounds__(256) void agg8_kernel(
        const unsigned char* __restrict__ h8, const int* __restrict__ offs,
        const int* __restrict__ csr, const float* __restrict__ rdeg,
        unsigned short* __restrict__ meanout, int N) {
    const int node = blockIdx.x * 4 + (threadIdx.x >> 6);
    const int lane = threadIdx.x & 63;
    if (node >= N) return;
    const int s0 = offs[node], s1 = offs[node + 1];
    const float r = rdeg[node];   // hoisted: overlaps with gathers
    const char* __restrict__ hb = (const char*)h8;
    const unsigned lane2 = (unsigned)lane * 2u;
    f32x2 acc = {0.f, 0.f};
    for (int base = s0; base < s1; base += 64) {
        const int cnt = min(64, s1 - base);
        const int boff = csr[base + min(lane, cnt - 1)] << 7;  // fp8 row byte offset
        if (cnt <= 31) {
            unsigned vA[16], vB[8], vC[4], vD[2], vE;
            int j = 0;
            // ---- issue phase: all loads in flight before any accumulate ----
            if (cnt & 16) {
                unsigned o[16];
#pragma unroll
                for (int k = 0; k < 16; ++k) o[k] = (unsigned)__shfl(boff, j + k, 64) + lane2;
#pragma unroll
                for (int k = 0; k < 16; ++k) vA[k] = *(const unsigned short*)(hb + o[k]);
                j += 16;
            }
            if (cnt & 8) {
                unsigned o[8];
#pragma unroll
                for (int k = 0; k < 8; ++k) o[k] = (unsigned)__shfl(boff, j + k, 64) + lane2;
#pragma unroll
                for (int k = 0; k < 8; ++k) vB[k] = *(const unsigned short*)(hb + o[k]);
                j += 8;
            }
            if (cnt & 4) {
                unsigned o[4];
#pragma unroll
                for (int k = 0; k < 4; ++k) o[k] = (unsigned)__shfl(boff, j + k, 64) + lane2;
#pragma unroll
                for (int k = 0; k < 4; ++k) vC[k] = *(const unsigned short*)(hb + o[k]);
                j += 4;
            }
            if (cnt & 2) {
                unsigned o[2];
#pragma unroll
                for (int k = 0; k < 2; ++k) o[k] = (unsigned)__shfl(boff, j + k, 64) + lane2;
#pragma unroll
                for (int k = 0; k < 2; ++k) vD[k] = *(const unsigned short*)(hb + o[k]);
                j += 2;
            }
            if (cnt & 1) {
                unsigned o = (unsigned)__shfl(boff, j, 64) + lane2;
                vE = *(const unsigned short*)(hb + o);
            }
            // ---- accumulate phase: same order as sequential version ----
            if (cnt & 16) {
#pragma unroll
                for (int k = 0; k < 16; ++k) acc += __builtin_amdgcn_cvt_pk_f32_fp8(vA[k], false);
            }
            if (cnt & 8) {
#pragma unroll
                for (int k = 0; k < 8; ++k) acc += __builtin_amdgcn_cvt_pk_f32_fp8(vB[k], false);
            }
            if (cnt & 4) {
#pragma unroll
                for (int k = 0; k < 4; ++k) acc += __builtin_amdgcn_cvt_pk_f32_fp8(vC[k], false);
            }
            if (cnt & 2) {
#pragma unroll
                for (int k = 0; k < 2; ++k) acc += __builtin_amdgcn_cvt_pk_f32_fp8(vD[k], false);
            }
            if (cnt & 1) acc += __builtin_amdgcn_cvt_pk_f32_fp8(vE, false);
        } else {
            int j = 0;
#define AGG8_GROUP(NG)                                                         \
            {                                                                  \
                unsigned o[NG];                                                \
                _Pragma("unroll")                                              \
                for (int k = 0; k < NG; ++k)                                   \
                    o[k] = (unsigned)__shfl(boff, j + k, 64) + lane2;          \
                unsigned int v[NG];                                            \
                _Pragma("unroll")                                              \
                for (int k = 0; k < NG; ++k)                                   \
                    v[k] = *(const unsigned short*)(hb + o[k]);                \
                _Pragma("unroll")                                              \
                for (int k = 0; k < NG; ++k)                                   \
                    acc += __builtin_amdgcn_cvt_pk_f32_fp8(v[k], false);       \
                j += NG;                                                       \
            }
            while (j + 16 <= cnt) AGG8_GROUP(16)
            if (cnt & 8) AGG8_GROUP(8)
            if (cnt & 4) AGG8_GROUP(4)
            if (cnt & 2) AGG8_GROUP(2)
            if (cnt & 1) AGG8_GROUP(1)
#undef AGG8_GROUP
        }
    }
    unsigned int o = (unsigned int)f2b(acc.x * r) | ((unsigned int)f2b(acc.y * r) << 16);
    *(unsigned int*)&meanout[(size_t)node * NF + lane * 2] = o;
}

// ---- layer-2 final agg: out[i] = mean_j zl[j] + zr[i]  (fp32 out) -----------
// Same issue-all-then-accumulate structure; zr load hoisted before the loop.

__global__ __launch_bounds__(256) void agg2_kernel(
        const unsigned short* __restrict__ z, const int* __restrict__ offs,
        const int* __restrict__ csr, const float* __restrict__ rdeg,
        float* __restrict__ out, int N) {
    const int node = blockIdx.x * 4 + (threadIdx.x >> 6);
    const int lane = threadIdx.x & 63;
    if (node >= N) return;
    const int s0 = offs[node], s1 = offs[node + 1];
    const float r = rdeg[node];
    const char* __restrict__ zb = (const char*)z;
    const unsigned lane2 = (unsigned)lane * 2u;
    const unsigned int vr = *(const unsigned short*)(zb + (size_t)node * 256 + 128 + lane2);
    float acc = 0.f;
    for (int base = s0; base < s1; base += 64) {
        const int cnt = min(64, s1 - base);
        const int boff = csr[base + min(lane, cnt - 1)] << 8;  // zl = first 128B of 256B row
        if (cnt <= 31) {
            unsigned vA[16], vB[8], vC[4], vD[2], vE;
            int j = 0;
            if (cnt & 16) {
                unsigned o[16];
#pragma unroll
                for (int k = 0; k < 16; ++k) o[k] = (unsigned)__shfl(boff, j + k, 64) + lane2;
#pragma unroll
                for (int k = 0; k < 16; ++k) vA[k] = *(const unsigned short*)(zb + o[k]);
                j += 16;
            }
            if (cnt & 8) {
                unsigned o[8];
#pragma unroll
                for (int k = 0; k < 8; ++k) o[k] = (unsigned)__shfl(boff, j + k, 64) + lane2;
#pragma unroll
                for (int k = 0; k < 8; ++k) vB[k] = *(const unsigned short*)(zb + o[k]);
                j += 8;
            }
            if (cnt & 4) {
                unsigned o[4];
#pragma unroll
                for (int k = 0; k < 4; ++k) o[k] = (unsigned)__shfl(boff, j + k, 64) + lane2;
#pragma unroll
                for (int k = 0; k < 4; ++k) vC[k] = *(const unsigned short*)(zb + o[k]);
                j += 4;
            }
            if (cnt & 2) {
                unsigned o[2];
#pragma unroll
                for (int k = 0; k < 2; ++k) o[k] = (unsigned)__shfl(boff, j + k, 64) + lane2;
#pragma unroll
                for (int k = 0; k < 2; ++k) vD[k] = *(const unsigned short*)(zb + o[k]);
                j += 2;
            }
            if (cnt & 1) {
                unsigned o = (unsigned)__shfl(boff, j, 64) + lane2;
                vE = *(const unsigned short*)(zb + o);
            }
            if (cnt & 16) {
#pragma unroll
                for (int k = 0; k < 16; ++k) acc += __uint_as_float(vA[k] << 16);
            }
            if (cnt & 8) {
#pragma unroll
                for (int k = 0; k < 8; ++k) acc += __uint_as_float(vB[k] << 16);
            }
            if (cnt & 4) {
#pragma unroll
                for (int k = 0; k < 4; ++k) acc += __uint_as_float(vC[k] << 16);
            }
            if (cnt & 2) {
#pragma unroll
                for (int k = 0; k < 2; ++k) acc += __uint_as_float(vD[k] << 16);
            }
            if (cnt & 1) acc += __uint_as_float(vE << 16);
        } else {
            int j = 0;
#define AGG2_GROUP(NG)                                                         \
            {                                                                  \
                unsigned o[NG];                                                \
                _Pragma("unroll")                                              \
                for (int k = 0; k < NG; ++k)                                   \
                    o[k] = (unsigned)__shfl(boff, j + k, 64) + lane2;          \
                unsigned int v[NG];                                            \
                _Pragma("unroll")                                              \
                for (int k = 0; k < NG; ++k)                                   \
                    v[k] = *(const unsigned short*)(zb + o[k]);                \
                _Pragma("unroll")                                              \
                for (int k = 0; k < NG; ++k)                                   \
                    acc += __uint_as_float(v[k] << 16);                        \
                j += NG;                                                       \
            }
            while (j + 16 <= cnt) AGG2_GROUP(16)
            if (cnt & 8) AGG2_GROUP(8)
            if (cnt & 4) AGG2_GROUP(4)
            if (cnt & 2) AGG2_GROUP(2)
            if (cnt & 1) AGG2_GROUP(1)
#undef AGG2_GROUP
        }
    }
    out[(size_t)node * 64 + lane] = acc * r + __uint_as_float(vr << 16);
}

// ------- MFMA GEMM (layers 0/1): out = [mean|h] @ Wcat^T + b, relu, bf16 out ---
// BM=64 x BN=64; BOTH A and W staged in LDS; coalesced transposed epilogue.

template <bool OUT8>
__global__ __launch_bounds__(256, 2) void gemm_kernel(
        const unsigned short* __restrict__ Abuf,   // mean [N][128] bf16
        const unsigned short* __restrict__ Hbuf,   // root [N][128] bf16
        const unsigned short* __restrict__ Wcat,   // [128][256] bf16
        const float* __restrict__ bias,            // [128] fp32
        unsigned short* __restrict__ outb,
        unsigned char* __restrict__ out8,
        int N) {
    __shared__ char LDS[65536];   // A 32KB | W 32KB; A region reused for transpose

    const int tid = threadIdx.x, wid = tid >> 6, lane = tid & 63;
    const int half = blockIdx.x & 1;
    const int m0 = (blockIdx.x >> 1) * 64;
    const int c0 = half * 64;
    char* Ac = LDS;
    char* Wc = LDS + 32768;
    const char* Ab = (const char*)Abuf;
    const char* Hb = (const char*)Hbuf;
    const char* Wb = (const char*)Wcat;

#pragma unroll
    for (int i = 0; i < 8; ++i) {
        int off = wid * 8192 + i * 1024 + lane * 16;
        int row = off >> 9, c = off & 511;
        int c2 = c ^ ((row & 7) << 4);
        int g = min(m0 + row, N - 1);
        const char* srcp = (c2 < 256) ? (Ab + (size_t)g * 256 + c2)
                                      : (Hb + (size_t)g * 256 + (c2 - 256));
        gld_lds16(srcp, Ac + wid * 8192 + i * 1024);
    }
#pragma unroll
    for (int i = 0; i < 8; ++i) {
        int off = wid * 8192 + i * 1024 + lane * 16;
        int row = off >> 9, c = off & 511;
        int c2 = c ^ ((row & 7) << 4);
        gld_lds16(Wb + (size_t)(c0 + row) * 512 + c2, Wc + wid * 8192 + i * 1024);
    }
    asm volatile("s_waitcnt vmcnt(0)" ::: "memory");
    __syncthreads();

    const int lm = lane & 15, ko = lane >> 4;
    const int wm = wid >> 1, wn = wid & 1;   // 2x2 waves, each 32x32 out

    f32x4 acc[2][2];
#pragma unroll
    for (int i = 0; i < 2; ++i)
#pragma unroll
        for (int j = 0; j < 2; ++j)
            acc[i][j] = (f32x4){0.f, 0.f, 0.f, 0.f};

#pragma unroll
    for (int ks = 0; ks < 8; ++ks) {
        const int kb = ks * 64 + ko * 16;
        bf16x8 a[2], b[2];
#pragma unroll
        for (int j = 0; j < 2; ++j) {
            int row = wn * 32 + j * 16 + lm;
            b[j] = *(const bf16x8*)(Wc + row * 512 + (kb ^ ((row & 7) << 4)));
        }
#pragma unroll
        for (int i = 0; i < 2; ++i) {
            int row = wm * 32 + i * 16 + lm;
            a[i] = *(const bf16x8*)(Ac + row * 512 + (kb ^ ((row & 7) << 4)));
        }
#pragma unroll
        for (int i = 0; i < 2; ++i)
#pragma unroll
            for (int j = 0; j < 2; ++j)
                acc[i][j] = __builtin_amdgcn_mfma_f32_16x16x32_bf16(b[j], a[i], acc[i][j], 0, 0, 0);
    }

    // ---- epilogue: bias+relu -> LDS transpose (144B-pad rows) -> coalesced ----
    __syncthreads();
#pragma unroll
    for (int i = 0; i < 2; ++i) {
        const int r = wm * 32 + i * 16 + lm;
#pragma unroll
        for (int j = 0; j < 2; ++j) {
            const int lcol = wn * 32 + j * 16 + ko * 4;
            const float4 bv = *(const float4*)&bias[c0 + lcol];
            float v0 = fmaxf(acc[i][j][0] + bv.x, 0.f);
            float v1 = fmaxf(acc[i][j][1] + bv.y, 0.f);
            float v2 = fmaxf(acc[i][j][2] + bv.z, 0.f);
            float v3 = fmaxf(acc[i][j][3] + bv.w, 0.f);
            uint2 o;
            o.x = (unsigned int)f2b(v0) | ((unsigned int)f2b(v1) << 16);
            o.y = (unsigned int)f2b(v2) | ((unsigned int)f2b(v3) << 16);
            *(uint2*)(Ac + r * 144 + lcol * 2) = o;
        }
    }
    __syncthreads();
#pragma unroll
    for (int p = 0; p < 2; ++p) {
        const int chunk = tid + p * 256;
        const int row = chunk >> 3;
        const int off = (chunk & 7) * 16;
        const int node = m0 + row;
        if (node >= N) continue;
        uint4 q = *(const uint4*)(Ac + row * 144 + off);
        *(uint4*)((char*)outb + (size_t)node * 256 + c0 * 2 + off) = q;
        if (OUT8) {
            float f0 = __uint_as_float(q.x << 16), f1 = __uint_as_float(q.x & 0xffff0000u);
            float f2 = __uint_as_float(q.y << 16), f3 = __uint_as_float(q.y & 0xffff0000u);
            float f4 = __uint_as_float(q.z << 16), f5 = __uint_as_float(q.z & 0xffff0000u);
            float f6 = __uint_as_float(q.w << 16), f7 = __uint_as_float(q.w & 0xffff0000u);
            unsigned p0 = __builtin_amdgcn_cvt_pk_fp8_f32(f0, f1, 0, false);
            p0 = __builtin_amdgcn_cvt_pk_fp8_f32(f2, f3, p0, true);
            unsigned p1 = __builtin_amdgcn_cvt_pk_fp8_f32(f4, f5, 0, false);
            p1 = __builtin_amdgcn_cvt_pk_fp8_f32(f6, f7, p1, true);
            uint2 o8 = make_uint2(p0, p1);
            *(uint2*)((char*)out8 + (size_t)node * 128 + c0 + (off >> 1)) = o8;
        }
    }
}

// ---------- MFMA GEMM (layer 2): z = h @ Wst^T + bst  (K=128, bf16 out) -------

__global__ __launch_bounds__(256, 2) void gemmz_kernel(
        const unsigned short* __restrict__ A,    // [N][128] bf16
        const unsigned short* __restrict__ W,    // [128][128] bf16
        const float* __restrict__ bias,          // [128] fp32
        unsigned short* __restrict__ outb,       // [N][128] bf16
        int N) {
    __shared__ char LDS[32768];   // A 16KB | W 16KB; A reused for transpose (9.2KB)

    const int tid = threadIdx.x, wid = tid >> 6, lane = tid & 63;
    const int half = blockIdx.x & 1;
    const int m0 = (blockIdx.x >> 1) * 64;
    const int c0 = half * 64;
    char* Ac = LDS;
    char* Wc = LDS + 16384;
    const char* Ab = (const char*)A;
    const char* Wb = (const char*)W;

#pragma unroll
    for (int i = 0; i < 4; ++i) {
        int off = wid * 4096 + i * 1024 + lane * 16;
        int row = off >> 8, c = off & 255;
        int c2 = c ^ ((row & 7) << 4);
        int g = min(m0 + row, N - 1);
        gld_lds16(Ab + (size_t)g * 256 + c2, Ac + wid * 4096 + i * 1024);
    }
#pragma unroll
    for (int i = 0; i < 4; ++i) {
        int off = wid * 4096 + i * 1024 + lane * 16;
        int row = off >> 8, c = off & 255;
        int c2 = c ^ ((row & 7) << 4);
        gld_lds16(Wb + (size_t)(c0 + row) * 256 + c2, Wc + wid * 4096 + i * 1024);
    }
    asm volatile("s_waitcnt vmcnt(0)" ::: "memory");
    __syncthreads();

    const int lm = lane & 15, ko = lane >> 4;
    const int wm = wid >> 1, wn = wid & 1;

    f32x4 acc[2][2];
#pragma unroll
    for (int i = 0; i < 2; ++i)
#pragma unroll
        for (int j = 0; j < 2; ++j)
            acc[i][j] = (f32x4){0.f, 0.f, 0.f, 0.f};

#pragma unroll
    for (int ks = 0; ks < 4; ++ks) {
        const int kb = ks * 64 + ko * 16;
        bf16x8 a[2], b[2];
#pragma unroll
        for (int j = 0; j < 2; ++j) {
            int row = wn * 32 + j * 16 + lm;
            b[j] = *(const bf16x8*)(Wc + row * 256 + (kb ^ ((row & 7) << 4)));
        }
#pragma unroll
        for (int i = 0; i < 2; ++i) {
            int row = wm * 32 + i * 16 + lm;
            a[i] = *(const bf16x8*)(Ac + row * 256 + (kb ^ ((row & 7) << 4)));
        }
#pragma unroll
        for (int i = 0; i < 2; ++i)
#pragma unroll
            for (int j = 0; j < 2; ++j)
                acc[i][j] = __builtin_amdgcn_mfma_f32_16x16x32_bf16(b[j], a[i], acc[i][j], 0, 0, 0);
    }

    __syncthreads();
#pragma unroll
    for (int i = 0; i < 2; ++i) {
        const int r = wm * 32 + i * 16 + lm;
#pragma unroll
        for (int j = 0; j < 2; ++j) {
            const int lcol = wn * 32 + j * 16 + ko * 4;
            const float4 bv = *(const float4*)&bias[c0 + lcol];
            uint2 o;
            o.x = (unsigned int)f2b(acc[i][j][0] + bv.x) |
                  ((unsigned int)f2b(acc[i][j][1] + bv.y) << 16);
            o.y = (unsigned int)f2b(acc[i][j][2] + bv.z) |
                  ((unsigned int)f2b(acc[i][j][3] + bv.w) << 16);
            *(uint2*)(Ac + r * 144 + lcol * 2) = o;
        }
    }
    __syncthreads();
#pragma unroll
    for (int p = 0; p < 2; ++p) {
        const int chunk = tid + p * 256;
        const int row = chunk >> 3;
        const int off = (chunk & 7) * 16;
        const int node = m0 + row;
        if (node >= N) continue;
        uint4 q = *(const uint4*)(Ac + row * 144 + off);
        *(uint4*)((char*)outb + (size_t)node * 256 + c0 * 2 + off) = q;
    }
}

// ---------------- launch ----------------

extern "C" void kernel_launch(void* const* d_in, const int* in_sizes, int n_in,
                              void* d_out, int out_size, void* d_ws, size_t ws_size,
                              hipStream_t stream) {
    const float* x   = (const float*)d_in[0];
    const int*   ei  = (const int*)d_in[1];
    const float* Wl0 = (const float*)d_in[2];
    const float* Wr0 = (const float*)d_in[3];
    const float* b0  = (const float*)d_in[4];
    const float* Wl1 = (const float*)d_in[5];
    const float* Wr1 = (const float*)d_in[6];
    const float* b1  = (const float*)d_in[7];
    const float* Wl2 = (const float*)d_in[8];
    const float* Wr2 = (const float*)d_in[9];
    const float* b2  = (const float*)d_in[10];
    float* out = (float*)d_out;

    const int N = in_sizes[0] / NF;
    const int E = in_sizes[1] / 2;
    const int* srcv = ei;
    const int* dstv = ei + E;

    const int NB   = (N + 255) >> 8;
    const int NBLK = (E + CHUNK - 1) / CHUNK;
    const int T    = NB * NBLK;
    const int NS   = (T + 255) / 256;

    char* w = (char*)d_ws;
    auto alloc = [&](size_t bytes) {
        void* p = (void*)w;
        w += (bytes + 255) & ~(size_t)255;
        return p;
    };
    unsigned short* xb   = (unsigned short*)alloc((size_t)N * NF * 2);
    unsigned short* h1b  = (unsigned short*)alloc((size_t)N * NF * 2);
    unsigned short* h2b  = (unsigned short*)alloc((size_t)N * NF * 2);
    unsigned short* mb   = (unsigned short*)alloc((size_t)N * NF * 2);
    // fp8 region (25.6 MB): x8 + h18 while live; z2b aliases it afterwards
    unsigned char*  u8   = (unsigned char*)alloc((size_t)N * NF * 2);
    unsigned char*  x8   = u8;                       // [N][128] fp8
    unsigned char*  h18  = u8 + (size_t)N * NF;      // [N][128] fp8
    unsigned short* z2b  = (unsigned short*)u8;      // [N][128] bf16 (after x8/h18 dead)
    unsigned short* Wc0  = (unsigned short*)alloc((size_t)128 * 256 * 2);
    unsigned short* Wc1  = (unsigned short*)alloc((size_t)128 * 256 * 2);
    unsigned short* Wst2 = (unsigned short*)alloc((size_t)128 * 128 * 2);
    float*          bst2 = (float*)alloc((size_t)128 * 4);
    int*   offs   = (int*)alloc((size_t)(N + 1) * 4);
    int*   csr    = (int*)alloc((size_t)E * 4);
    float* rdeg   = (float*)alloc((size_t)N * 4);
    unsigned int* recs = (unsigned int*)alloc((size_t)E * 4);
    int*   hist   = (int*)alloc((size_t)T * 4);
    int*   base   = (int*)alloc((size_t)T * 4);
    int*   bstart = (int*)alloc((size_t)(NB + 1) * 4);
    int*   sb1    = (int*)alloc((size_t)1024 * 4);
    int*   sb2    = (int*)alloc((size_t)1024 * 4);

    const int n4 = N * NF / 4;
    const int bCvt = (n4 + 255) / 256;
    const int bW0  = bCvt + 64;            // wcat0: 16384/256
    const int bW1  = bW0 + 64;             // wcat1
    const int bWs  = bW1 + 32;             // wstack: 8192/256
    const int bTot = bWs + NBLK;           // + hist

    prep_kernel<<<bTot, 256, 0, stream>>>(x, xb, x8, n4,
                                          Wl0, Wr0, Wc0, Wl1, Wr1, Wc1,
                                          Wl2, Wr2, b2, Wst2, bst2,
                                          dstv, hist, E, NB,
                                          bCvt, bW0, bW1, bWs);
    sb_sum<<<NS, 256, 0, stream>>>(hist, sb1, T, NB, NBLK);
    sb_scan<<<1, 1024, 0, stream>>>(sb1, sb2, NS);
    sb_apply<<<NS, 256, 0, stream>>>(hist, sb2, base, bstart, T, NB, NBLK, E);
    scat_kernel<<<NBLK, 256, 0, stream>>>(srcv, dstv, base, recs, E, NB, NBLK);
    csr_kernel<<<NB, 256, 0, stream>>>(recs, bstart, offs, rdeg, csr, N, E);

    const int ab  = (N + 3) / 4;
    const int gb2 = 2 * ((N + 63) / 64);   // (mtile, colHalf) grid

    // layer 0: mean from fp8 x; gemm also emits fp8 h1 for next gather
    agg8_kernel<<<ab, 256, 0, stream>>>(x8, offs, csr, rdeg, mb, N);
    gemm_kernel<true><<<gb2, 256, 0, stream>>>(mb, xb, Wc0, b0, h1b, h18, N);

    // layer 1: mean from fp8 h1, root bf16 h1
    agg8_kernel<<<ab, 256, 0, stream>>>(h18, offs, csr, rdeg, mb, N);
    gemm_kernel<false><<<gb2, 256, 0, stream>>>(mb, h1b, Wc1, b1, h2b, nullptr, N);

    // layer 2: transform-first (bf16), fused final agg
    gemmz_kernel<<<gb2, 256, 0, stream>>>(h2b, Wst2, bst2, z2b, N);
    agg2_kernel<<<ab, 256, 0, stream>>>(z2b, offs, csr, rdeg, out, N);
}